// Round 10
// baseline (448.083 us; speedup 1.0000x reference)
//
#include <hip/hip_runtime.h>
#include <cstdint>

// ---------------------------------------------------------------------------
// SA_Layer_PN2: centers + 32-NN + (gather,concat) -> 3x [1x1conv -> BN -> ReLU]
// -> max over k.  f32 math, bf16 activation storage.
// R14-R19: k_knn ladder (105us, VALU-bound 77%, FROZEN).
// R22: k_l1/k_l2 MFMA + fused stats (534 -> 383us).
// R23: middle kernels were latency-bound at 4 blocks/CU (k_l3 steady: occ
// 17.8%, MfmaUtil 3%, HBM 5% — nothing saturated). Now 2048 blocks x 2
// centers/wave (8 blocks/CU, halved per-wave serial chain); k_l1/k_l2
// transpose tile stores bf16 BITS (ushort[16][72], 144B rows: uint4-aligned,
// <=2-way bank alias) so LDS fits 8 blocks/CU; k_l1 prefetches knn/xyz4 for
// both r-tiles per center (breaks gather dependency chain). z bits and
// selection identical; stats order shifts by ulp (headroom 0.0625 vs 0.121).
// d2key expression UNCHANGED (verified contract — do not touch).
// ---------------------------------------------------------------------------

constexpr int B_ = 8;
constexpr int N_ = 8192;
constexpr int M_ = 2048;
constexpr int K_ = 32;
constexpr float NTINV = 1.0f / 524288.0f;   // 1 / (B*M*K)
constexpr float BN_EPS = 1e-5f;

// workspace layout (bytes)
constexpr size_t OFF_KNN   = 0;             // int32 [B*M*K]          2,097,152
constexpr size_t OFF_FEATB = 2097152;       // bf16 [B*N*64]          8,388,608
constexpr size_t OFF_MAXZ  = 2097152;       // f32 [16384*128] ALIASES featB (dead after k_l1)
constexpr size_t OFF_XYZ4  = 10485760;      // f32x4 [B*N]            2,097,152
constexpr size_t OFF_XN    = 12582912;      // f32 [B*N]                262,144
constexpr size_t OFF_WT1   = 12845056;      // f32 [67*64]               17,152
constexpr size_t OFF_WT2   = 12862208;      // f32 [64*64]               16,384
constexpr size_t OFF_WT3   = 12878592;      // bf16 frags [8192]         16,384
constexpr size_t OFF_W1F   = 12894976;      // bf16 frags [4096]          8,192
constexpr size_t OFF_W2F   = 12903168;      // bf16 frags [4096]          8,192
constexpr size_t OFF_GST   = 12911360;      // f32 [512]
constexpr size_t OFF_SS1   = 12913408;      // f32 [128]
constexpr size_t OFF_SS2   = 12913920;      // f32 [128]
constexpr size_t OFF_Z     = 12914432;      // bf16 [524288*64]      67,108,864
constexpr size_t WS_NEED   = 80023296;      // ~80 MB total

typedef __attribute__((ext_vector_type(8))) short bf16x8;
typedef __attribute__((ext_vector_type(4))) float f32x4;

// ---- bf16 helpers (RNE) ----------------------------------------------------
__device__ __forceinline__ unsigned int pack_bf2(float a, float b) {
  unsigned int ua = __float_as_uint(a);
  unsigned int ub = __float_as_uint(b);
  ua = ua + 0x7FFFu + ((ua >> 16) & 1u);
  ub = ub + 0x7FFFu + ((ub >> 16) & 1u);
  return (ua >> 16) | (ub & 0xFFFF0000u);
}
__device__ __forceinline__ float bf_lo(unsigned int u) { return __uint_as_float(u << 16); }
__device__ __forceinline__ float bf_hi(unsigned int u) { return __uint_as_float(u & 0xFFFF0000u); }

// monotone key — VERIFIED expression (R2/R14/R18). Single inlined definition
// => identical lowering at every call site (pass1/pass2/fallback consistent).
__device__ __forceinline__ unsigned int d2key(const float4 pv, float cx, float cy,
                                              float cz, float cb) {
  const float dot = cx * pv.x + cy * pv.y + cz * pv.z;
  const float d2 = (cb + pv.w) - 2.0f * dot;          // same formula as ref
  const unsigned int bits = __float_as_uint(d2);
  return bits ^ ((unsigned int)((int)bits >> 31) | 0x80000000u);
}
__device__ __forceinline__ int cindex(int m) {
  return (int)(((long long)m * (N_ - 1)) / (M_ - 1));
}

// ---------------------------------------------------------------------------
// k_prep: featB (bf16) pack, xyz4 pad (norm in .w), weight transposes,
// centers, + W3/W1(cols 3..66)/W2 packed as MFMA B-fragments.
// ---------------------------------------------------------------------------
__global__ __launch_bounds__(256) void k_prep(
    const float* __restrict__ xyz, const float* __restrict__ feat,
    const float* __restrict__ W1, const float* __restrict__ W2,
    const float* __restrict__ W3,
    unsigned short* __restrict__ featB, float* __restrict__ xyz4,
    float* __restrict__ xn,
    float* __restrict__ wt1, float* __restrict__ wt2,
    unsigned short* __restrict__ wt3f,
    unsigned short* __restrict__ w1f, unsigned short* __restrict__ w2f,
    float* __restrict__ cent_out)
{
  const int id = blockIdx.x * 256 + threadIdx.x;
  if (id < B_ * N_) {
    const int b = id >> 13;
    const int n = id & (N_ - 1);
    const float* pp = xyz + id * 3;
    const float x = pp[0], y = pp[1], z = pp[2];
    const float nrm = x * x + y * y + z * z;
    xn[id] = nrm;
    float4* x4 = (float4*)xyz4;
    x4[id] = make_float4(x, y, z, nrm);
    const float* fsrc = feat + b * 64 * N_ + n;
    unsigned short* fdst = featB + (size_t)id * 64;
#pragma unroll
    for (int c8 = 0; c8 < 8; ++c8) {
      uint4 v;
      v.x = pack_bf2(fsrc[(c8 * 8 + 0) * N_], fsrc[(c8 * 8 + 1) * N_]);
      v.y = pack_bf2(fsrc[(c8 * 8 + 2) * N_], fsrc[(c8 * 8 + 3) * N_]);
      v.z = pack_bf2(fsrc[(c8 * 8 + 4) * N_], fsrc[(c8 * 8 + 5) * N_]);
      v.w = pack_bf2(fsrc[(c8 * 8 + 6) * N_], fsrc[(c8 * 8 + 7) * N_]);
      *(uint4*)(fdst + c8 * 8) = v;
    }
  } else if (id < B_ * N_ + B_ * M_) {
    const int idx = id - B_ * N_;
    const int b = idx >> 11;
    const int m = idx & (M_ - 1);
    const int ic = cindex(m);
    const float* cp = xyz + (b * N_ + ic) * 3;
    float* dst = cent_out + idx * 3;
    dst[0] = cp[0]; dst[1] = cp[1]; dst[2] = cp[2];
  } else if (id < 81920 + 4288) {
    const int i = id - 81920;
    const int c = i >> 6, o = i & 63;
    wt1[i] = W1[o * 67 + c];
  } else if (id < 86208 + 4096) {
    const int i = id - 86208;
    const int c = i >> 6, o = i & 63;
    wt2[c * 64 + o] = W2[o * 64 + c];
  } else if (id < 90304 + 1024) {
    const int f = id - 90304;           // f = (ct*2+ks)*64 + lane, ct 0..7
    const int ct = f >> 7;
    const int ks = (f >> 6) & 1;
    const int lane = f & 63;
    const int quad = lane >> 4;
    const int col = lane & 15;
    const int n = ct * 16 + col;
    const int kb = ks * 32 + quad * 8;
    const float* wr = W3 + n * 64 + kb;
    uint4 v;
    v.x = pack_bf2(wr[0], wr[1]);
    v.y = pack_bf2(wr[2], wr[3]);
    v.z = pack_bf2(wr[4], wr[5]);
    v.w = pack_bf2(wr[6], wr[7]);
    ((uint4*)wt3f)[f] = v;
  } else if (id < 91328 + 512) {
    const int f = id - 91328;           // W2 fragments: ct 0..3
    const int ct = f >> 7;
    const int ks = (f >> 6) & 1;
    const int lane = f & 63;
    const int quad = lane >> 4;
    const int col = lane & 15;
    const int n = ct * 16 + col;
    const int kb = ks * 32 + quad * 8;
    const float* wr = W2 + n * 64 + kb;
    uint4 v;
    v.x = pack_bf2(wr[0], wr[1]);
    v.y = pack_bf2(wr[2], wr[3]);
    v.z = pack_bf2(wr[4], wr[5]);
    v.w = pack_bf2(wr[6], wr[7]);
    ((uint4*)w2f)[f] = v;
  } else if (id < 91840 + 512) {
    const int f = id - 91840;           // W1 fragments (input cols 3..66)
    const int ct = f >> 7;
    const int ks = (f >> 6) & 1;
    const int lane = f & 63;
    const int quad = lane >> 4;
    const int col = lane & 15;
    const int n = ct * 16 + col;
    const int kb = ks * 32 + quad * 8;
    const float* wr = W1 + n * 67 + 3 + kb;
    uint4 v;
    v.x = pack_bf2(wr[0], wr[1]);
    v.y = pack_bf2(wr[2], wr[3]);
    v.z = pack_bf2(wr[4], wr[5]);
    v.w = pack_bf2(wr[6], wr[7]);
    ((uint4*)w1f)[f] = v;
  }
}

// ---------------------------------------------------------------------------
// k_knn R19: one block = 4 centers. Occupancy-tuned. FROZEN.
// ---------------------------------------------------------------------------
__global__ __launch_bounds__(256, 4) void k_knn(
    const float* __restrict__ xyz, const float* __restrict__ xyz4,
    int* __restrict__ knn)
{
  __shared__ unsigned int hist4[4][1024];       // 16 KB; reused as keys2[4][512]
  __shared__ int sh_cnt[4], sh_B4[4], wsum4[4][4];
  __shared__ unsigned long long wbest[4];

  unsigned long long* keys2 = (unsigned long long*)hist4;

  const int t = threadIdx.x;
  const int lane = t & 63;
  const int w = t >> 6;
  const int bid = blockIdx.x;
  const int b = bid >> 9;
  const int m0 = (bid & 511) * 4;
  const int row_base = (b * M_ + m0) * K_;
  const float4* pts = ((const float4*)xyz4) + b * N_;

  // centers (block-uniform scalar loads)
  const float* cp0 = xyz + (b * N_ + cindex(m0 + 0)) * 3;
  const float* cp1 = xyz + (b * N_ + cindex(m0 + 1)) * 3;
  const float* cp2 = xyz + (b * N_ + cindex(m0 + 2)) * 3;
  const float* cp3 = xyz + (b * N_ + cindex(m0 + 3)) * 3;
  const float cx0 = cp0[0], cy0 = cp0[1], cz0 = cp0[2];
  const float cx1 = cp1[0], cy1 = cp1[1], cz1 = cp1[2];
  const float cx2 = cp2[0], cy2 = cp2[1], cz2 = cp2[2];
  const float cx3 = cp3[0], cy3 = cp3[1], cz3 = cp3[2];
  const float cb0 = cx0 * cx0 + cy0 * cy0 + cz0 * cz0;
  const float cb1 = cx1 * cx1 + cy1 * cy1 + cz1 * cz1;
  const float cb2 = cx2 * cx2 + cy2 * cy2 + cz2 * cz2;
  const float cb3 = cx3 * cx3 + cy3 * cy3 + cz3 * cz3;

  // zero hist (16 KB) + counters
  {
    uint4* hz = (uint4*)hist4;
    const uint4 z4 = make_uint4(0u, 0u, 0u, 0u);
#pragma unroll
    for (int i = 0; i < 4; ++i) hz[t * 4 + i] = z4;
  }
  if (t < 4) sh_cnt[t] = 0;
  __syncthreads();

  // ---- pass 1: stream points once (batch-8 chunks), 4 running minima ----
  unsigned int um0 = 0xFFFFFFFFu, um1 = 0xFFFFFFFFu;
  unsigned int um2 = 0xFFFFFFFFu, um3 = 0xFFFFFFFFu;
#pragma unroll 1
  for (int jo = 0; jo < 4; ++jo) {
    float4 pv8[8];
#pragma unroll
    for (int ji = 0; ji < 8; ++ji) pv8[ji] = pts[t + 256 * (jo * 8 + ji)];
#pragma unroll
    for (int ji = 0; ji < 8; ++ji) {
      const float4 pv = pv8[ji];
      const unsigned int k0 = d2key(pv, cx0, cy0, cz0, cb0);
      const unsigned int k1 = d2key(pv, cx1, cy1, cz1, cb1);
      const unsigned int k2 = d2key(pv, cx2, cy2, cz2, cb2);
      const unsigned int k3 = d2key(pv, cx3, cy3, cz3, cb3);
      um0 = um0 < k0 ? um0 : k0;
      um1 = um1 < k1 ? um1 : k1;
      um2 = um2 < k2 ? um2 : k2;
      um3 = um3 < k3 ? um3 : k3;
    }
  }
  atomicAdd(&hist4[0][um0 >> 22], 1u);
  atomicAdd(&hist4[1][um1 >> 22], 1u);
  atomicAdd(&hist4[2][um2 >> 22], 1u);
  atomicAdd(&hist4[3][um3 >> 22], 1u);
  __syncthreads();

  // ---- fused 4 scans: thread t owns slots [4t, 4t+4) of each hist4[s] ----
  {
    unsigned int h4[4][4], incl[4], sum[4];
#pragma unroll
    for (int s = 0; s < 4; ++s) {
      const uint4 ha = ((const uint4*)&hist4[s][0])[t];
      h4[s][0] = ha.x; h4[s][1] = ha.y; h4[s][2] = ha.z; h4[s][3] = ha.w;
      sum[s] = ha.x + ha.y + ha.z + ha.w;
      incl[s] = sum[s];
    }
#pragma unroll
    for (int off = 1; off < 64; off <<= 1) {
#pragma unroll
      for (int s = 0; s < 4; ++s) {
        const unsigned int v = __shfl_up(incl[s], off);
        if (lane >= off) incl[s] += v;
      }
    }
    if (lane == 63) {
#pragma unroll
      for (int s = 0; s < 4; ++s) wsum4[s][w] = (int)incl[s];
    }
    __syncthreads();
#pragma unroll
    for (int s = 0; s < 4; ++s) {
      unsigned int wpre = 0;
#pragma unroll
      for (int i = 0; i < 4; ++i) wpre += (i < w) ? (unsigned int)wsum4[s][i] : 0u;
      const unsigned int excl = wpre + incl[s] - sum[s];   // minima in slots < 4t
      unsigned int run = excl;
      int Bq = -1;
#pragma unroll
      for (int q = 0; q < 4; ++q) { run += h4[s][q]; if (Bq < 0 && run >= 33) Bq = t * 4 + q; }
      if (Bq >= 0 && excl < 33) sh_B4[s] = Bq;             // unique crossing thread
    }
    __syncthreads();                                       // sh_B4 visible
  }

  const unsigned int Bb0 = (unsigned int)sh_B4[0];
  const unsigned int Bb1 = (unsigned int)sh_B4[1];
  const unsigned int Bb2 = (unsigned int)sh_B4[2];
  const unsigned int Bb3 = (unsigned int)sh_B4[3];

  // ---- pass 2: stream once more (batch-8), compact candidates ----
#pragma unroll 1
  for (int jo = 0; jo < 4; ++jo) {
    float4 pv8[8];
#pragma unroll
    for (int ji = 0; ji < 8; ++ji) pv8[ji] = pts[t + 256 * (jo * 8 + ji)];
#pragma unroll
    for (int ji = 0; ji < 8; ++ji) {
      const float4 pv = pv8[ji];
      const unsigned int idx = (unsigned int)(t + 256 * (jo * 8 + ji));
      const unsigned int k0 = d2key(pv, cx0, cy0, cz0, cb0);
      const unsigned int k1 = d2key(pv, cx1, cy1, cz1, cb1);
      const unsigned int k2 = d2key(pv, cx2, cy2, cz2, cb2);
      const unsigned int k3 = d2key(pv, cx3, cy3, cz3, cb3);
      if ((k0 >> 22) <= Bb0) {
        const int pos = atomicAdd(&sh_cnt[0], 1);
        if (pos < 512) keys2[0 * 512 + pos] = ((unsigned long long)k0 << 32) | idx;
      }
      if ((k1 >> 22) <= Bb1) {
        const int pos = atomicAdd(&sh_cnt[1], 1);
        if (pos < 512) keys2[1 * 512 + pos] = ((unsigned long long)k1 << 32) | idx;
      }
      if ((k2 >> 22) <= Bb2) {
        const int pos = atomicAdd(&sh_cnt[2], 1);
        if (pos < 512) keys2[2 * 512 + pos] = ((unsigned long long)k2 << 32) | idx;
      }
      if ((k3 >> 22) <= Bb3) {
        const int pos = atomicAdd(&sh_cnt[3], 1);
        if (pos < 512) keys2[3 * 512 + pos] = ((unsigned long long)k3 << 32) | idx;
      }
    }
  }
  __syncthreads();

  // ---- rank: wave w ranks center w (exact 64-bit rank, broadcast reads) ----
  {
    const int C = sh_cnt[w];
    if (C <= 512) {
      const unsigned long long* kk = keys2 + w * 512;
      int* row = knn + row_base + w * K_;
      for (int i = lane; i < C; i += 64) {
        const unsigned long long k = kk[i];
        int r = 0;
        for (int q = 0; q < C; ++q) r += (kk[q] < k) ? 1 : 0;
        if (r < K_) row[r] = (int)(k & 0xFFFFFFFFull);
      }
    }
  }
  __syncthreads();

  // ---- fallback (practically never): exact 32-round extraction ----
#pragma unroll
  for (int s = 0; s < 4; ++s) {
    if (sh_cnt[s] > 512) {                         // block-uniform
      const float cx = (s == 0) ? cx0 : (s == 1) ? cx1 : (s == 2) ? cx2 : cx3;
      const float cy = (s == 0) ? cy0 : (s == 1) ? cy1 : (s == 2) ? cy2 : cy3;
      const float cz = (s == 0) ? cz0 : (s == 1) ? cz1 : (s == 2) ? cz2 : cz3;
      const float cb = (s == 0) ? cb0 : (s == 1) ? cb1 : (s == 2) ? cb2 : cb3;
      unsigned int uu[32];
#pragma unroll
      for (int j = 0; j < 32; ++j) uu[j] = d2key(pts[t + 256 * j], cx, cy, cz, cb);
      int* row = knn + row_base + s * K_;
#pragma unroll 1
      for (int r = 0; r < K_; ++r) {
        unsigned long long best = 0xFFFFFFFFFFFFFFFFull;
#pragma unroll
        for (int j = 0; j < 32; ++j) {
          unsigned long long k = ((unsigned long long)uu[j] << 32) | (unsigned int)(t + 256 * j);
          best = (k < best) ? k : best;
        }
#pragma unroll
        for (int off = 1; off < 64; off <<= 1) {
          unsigned long long o = __shfl_xor(best, off);
          best = (o < best) ? o : best;
        }
        if (lane == 0) wbest[w] = best;
        __syncthreads();
        unsigned long long b01 = wbest[0] < wbest[1] ? wbest[0] : wbest[1];
        unsigned long long b23 = wbest[2] < wbest[3] ? wbest[2] : wbest[3];
        best = b01 < b23 ? b01 : b23;
        if (t == 0) row[r] = (int)(best & 0xFFFFFFFFull);
        const int n_match = (int)(best & 0xFFFFFFFFull);
#pragma unroll
        for (int j = 0; j < 32; ++j)
          if ((t + 256 * j) == n_match) uu[j] = 0xFFFFFFFFu;
        __syncthreads();
      }
    }
  }
}

// ---------------------------------------------------------------------------
// k_l1 v6 (MFMA): 2048 blocks, 2 centers/wave (8 blocks/CU). A-frag =
// gathered featB row (bf16 direct). B-frag = w1f. knn/xyz4 prefetched for
// both r-tiles per center. Epilogue adds f32 local-xyz part + b1, rounds to
// bf16 BITS stored in ushort tile [16][72] (144B rows, uint4-aligned),
// fused layer-1 stats, coalesced z store.
// ---------------------------------------------------------------------------
__global__ __launch_bounds__(256, 4) void k_l1(
    const float* __restrict__ xyz4, const unsigned short* __restrict__ featB,
    const int* __restrict__ knn, const float* __restrict__ centers,
    const float* __restrict__ wt1, const float* __restrict__ bias,
    const unsigned short* __restrict__ w1f,
    unsigned short* __restrict__ zout, float* __restrict__ gstats)
{
  __shared__ unsigned short wfl[4096];        // 8 KB W1 fragments
  __shared__ unsigned short tpu[4][16][72];   // 9 KB bf16-bit transpose tiles
  __shared__ float ls[128];
  const int t = threadIdx.x;
  const int lane = t & 63;
  const int w = t >> 6;
  const int quad = lane >> 4;
  const int col = lane & 15;

  {
    const uint4* src = (const uint4*)w1f;
    uint4* dst = (uint4*)wfl;
    dst[t] = src[t];
    dst[t + 256] = src[t + 256];
  }
  if (t < 128) ls[t] = 0.0f;
  __syncthreads();

  // per-lane channel consts: ch = ct*16+col
  float w1x[4], w1y[4], w1z[4], b14[4];
#pragma unroll
  for (int ct = 0; ct < 4; ++ct) {
    const int ch = ct * 16 + col;
    w1x[ct] = wt1[ch];
    w1y[ct] = wt1[64 + ch];
    w1z[ct] = wt1[128 + ch];
    b14[ct] = bias[ch];
  }

  float sacc[4] = {0.f, 0.f, 0.f, 0.f};
  float qacc[4] = {0.f, 0.f, 0.f, 0.f};

  const int c0 = blockIdx.x * 8 + w * 2;      // 2048 blocks, 8 centers each

#pragma unroll 1
  for (int ci = 0; ci < 2; ++ci) {
    const int c = c0 + ci;                    // global center id
    const int b = c >> 11;
    const float* cp = centers + c * 3;        // wave-uniform
    const float cx = cp[0], cy = cp[1], cz = cp[2];

    // prefetch both r-tiles' gather state (breaks knn->featB chain)
    const int nnA = knn[c * 32 + col];
    const int nnB = knn[c * 32 + 16 + col];
    const float4 pvA = ((const float4*)xyz4)[b * N_ + nnA];
    const float4 pvB = ((const float4*)xyz4)[b * N_ + nnB];

#pragma unroll 1
    for (int rt = 0; rt < 2; ++rt) {
      const int pbase = c * 32 + rt * 16;
      const int nn = rt ? nnB : nnA;
      const float4 pv = rt ? pvB : pvA;
      const size_t frow = ((size_t)b * N_ + nn) * 64;
      const float l0 = pv.x - cx;
      const float l1 = pv.y - cy;
      const float l2 = pv.z - cz;

      bf16x8 afr[2];
#pragma unroll
      for (int ks = 0; ks < 2; ++ks) {
        union { uint4 u; bf16x8 v; } cv;
        cv.u = *(const uint4*)(featB + frow + ks * 32 + quad * 8);
        afr[ks] = cv.v;
      }

      f32x4 acc[4];
#pragma unroll
      for (int ct = 0; ct < 4; ++ct) acc[ct] = (f32x4){0.f, 0.f, 0.f, 0.f};
#pragma unroll
      for (int ct = 0; ct < 4; ++ct) {
        const bf16x8 b0 = *(const bf16x8*)(wfl + ((ct * 2 + 0) * 64 + lane) * 8);
        const bf16x8 b1 = *(const bf16x8*)(wfl + ((ct * 2 + 1) * 64 + lane) * 8);
        acc[ct] = __builtin_amdgcn_mfma_f32_16x16x32_bf16(afr[0], b0, acc[ct], 0, 0, 0);
        acc[ct] = __builtin_amdgcn_mfma_f32_16x16x32_bf16(afr[1], b1, acc[ct], 0, 0, 0);
      }

      // epilogue: + local_xyz part (f32) + bias, round, stats, bf16-bit tile
#pragma unroll
      for (int i = 0; i < 4; ++i) {
        const int srcl = quad * 4 + i;        // D point row = quad*4+i
        const float lx = __shfl(l0, srcl);
        const float ly = __shfl(l1, srcl);
        const float lz = __shfl(l2, srcl);
#pragma unroll
        for (int ct = 0; ct < 4; ++ct) {
          const float v = fmaf(lx, w1x[ct],
                          fmaf(ly, w1y[ct],
                          fmaf(lz, w1z[ct], b14[ct]))) + acc[ct][i];
          unsigned int u = __float_as_uint(v);
          u = u + 0x7FFFu + ((u >> 16) & 1u);
          const unsigned short hb = (unsigned short)(u >> 16);
          const float rv = __uint_as_float((unsigned int)hb << 16);
          sacc[ct] += rv;
          qacc[ct] = fmaf(rv, rv, qacc[ct]);
          tpu[w][quad * 4 + i][ct * 16 + col] = hb;
        }
      }
      asm volatile("s_waitcnt lgkmcnt(0)" ::: "memory");

      // transpose store: lane -> point (lane>>2), channel chunk (lane&3)*16
      {
        const int pi = lane >> 2, cc = lane & 3;
        const uint4* tr = (const uint4*)&tpu[w][pi][cc * 16];
        const uint4 a = tr[0];
        const uint4 bq = tr[1];
        unsigned short* zp = zout + (size_t)(pbase + pi) * 64 + cc * 16;
        *(uint4*)zp = a;
        *(uint4*)(zp + 8) = bq;
      }
      asm volatile("s_waitcnt lgkmcnt(0)" ::: "memory");
    }
  }

  // fused layer-1 stats: channel ct*16+col replicated across quads
#pragma unroll
  for (int ct = 0; ct < 4; ++ct) {
    float sv = sacc[ct], qv = qacc[ct];
    sv += __shfl_xor(sv, 16);
    sv += __shfl_xor(sv, 32);
    qv += __shfl_xor(qv, 16);
    qv += __shfl_xor(qv, 32);
    if (quad == 0) {
      atomicAdd(&ls[ct * 16 + col], sv);
      atomicAdd(&ls[64 + ct * 16 + col], qv);
    }
  }
  __syncthreads();
  if (t < 128) atomicAdd(&gstats[t], ls[t]);  // s[0..63], q[64..127]
}

// ---------------------------------------------------------------------------
// k_l2 v3 (MFMA, in-place, fused layer-2 stats): 2048 blocks, 2 centers/wave.
// A-frag = z row + BN1/ReLU (ss1); B-frag = w2f. Epilogue: +b2, round to
// bf16 bits (ushort tile), stats, coalesced in-place z store.
// ---------------------------------------------------------------------------
__global__ __launch_bounds__(256, 4) void k_l2(
    unsigned short* __restrict__ z, const unsigned short* __restrict__ w2f,
    const float* __restrict__ bias, const float* __restrict__ ss,
    float* __restrict__ gstats)
{
  __shared__ unsigned short wfl[4096];        // 8 KB W2 fragments
  __shared__ unsigned short tpu[4][16][72];   // 9 KB
  __shared__ float ls[128];
  __shared__ float ssl[128];
  const int t = threadIdx.x;
  const int lane = t & 63;
  const int w = t >> 6;
  const int quad = lane >> 4;
  const int col = lane & 15;

  {
    const uint4* src = (const uint4*)w2f;
    uint4* dst = (uint4*)wfl;
    dst[t] = src[t];
    dst[t + 256] = src[t + 256];
  }
  if (t < 128) { ssl[t] = ss[t]; ls[t] = 0.0f; }
  __syncthreads();

  const float4* scv = (const float4*)ssl;
  const float4* shv = (const float4*)(ssl + 64);

  float b24[4];
#pragma unroll
  for (int ct = 0; ct < 4; ++ct) b24[ct] = bias[ct * 16 + col];

  float sacc[4] = {0.f, 0.f, 0.f, 0.f};
  float qacc[4] = {0.f, 0.f, 0.f, 0.f};

  const int c0 = blockIdx.x * 8 + w * 2;

#pragma unroll 1
  for (int ci = 0; ci < 2; ++ci) {
    const int c = c0 + ci;
#pragma unroll 1
    for (int rt = 0; rt < 2; ++rt) {
      const int pbase = c * 32 + rt * 16;
      const int prow = pbase + col;

      // A-build: load 16B of z, BN1+ReLU, repack bf16 (k_l3 pattern)
      bf16x8 afr[2];
#pragma unroll
      for (int ks = 0; ks < 2; ++ks) {
        const int k0 = ks * 32 + quad * 8;
        const uint4 raw = *(const uint4*)(z + (size_t)prow * 64 + k0);
        const float4 s0 = scv[k0 >> 2], s1 = scv[(k0 >> 2) + 1];
        const float4 h0 = shv[k0 >> 2], h1 = shv[(k0 >> 2) + 1];
        const float f0 = fmaxf(0.0f, fmaf(bf_lo(raw.x), s0.x, h0.x));
        const float f1 = fmaxf(0.0f, fmaf(bf_hi(raw.x), s0.y, h0.y));
        const float f2 = fmaxf(0.0f, fmaf(bf_lo(raw.y), s0.z, h0.z));
        const float f3 = fmaxf(0.0f, fmaf(bf_hi(raw.y), s0.w, h0.w));
        const float f4 = fmaxf(0.0f, fmaf(bf_lo(raw.z), s1.x, h1.x));
        const float f5 = fmaxf(0.0f, fmaf(bf_hi(raw.z), s1.y, h1.y));
        const float f6 = fmaxf(0.0f, fmaf(bf_lo(raw.w), s1.z, h1.z));
        const float f7 = fmaxf(0.0f, fmaf(bf_hi(raw.w), s1.w, h1.w));
        union { uint4 u; bf16x8 v; } cv;
        cv.u.x = pack_bf2(f0, f1);
        cv.u.y = pack_bf2(f2, f3);
        cv.u.z = pack_bf2(f4, f5);
        cv.u.w = pack_bf2(f6, f7);
        afr[ks] = cv.v;
      }

      f32x4 acc[4];
#pragma unroll
      for (int ct = 0; ct < 4; ++ct) acc[ct] = (f32x4){0.f, 0.f, 0.f, 0.f};
#pragma unroll
      for (int ct = 0; ct < 4; ++ct) {
        const bf16x8 b0 = *(const bf16x8*)(wfl + ((ct * 2 + 0) * 64 + lane) * 8);
        const bf16x8 b1 = *(const bf16x8*)(wfl + ((ct * 2 + 1) * 64 + lane) * 8);
        acc[ct] = __builtin_amdgcn_mfma_f32_16x16x32_bf16(afr[0], b0, acc[ct], 0, 0, 0);
        acc[ct] = __builtin_amdgcn_mfma_f32_16x16x32_bf16(afr[1], b1, acc[ct], 0, 0, 0);
      }

#pragma unroll
      for (int i = 0; i < 4; ++i) {
#pragma unroll
        for (int ct = 0; ct < 4; ++ct) {
          const float v = acc[ct][i] + b24[ct];
          unsigned int u = __float_as_uint(v);
          u = u + 0x7FFFu + ((u >> 16) & 1u);
          const unsigned short hb = (unsigned short)(u >> 16);
          const float rv = __uint_as_float((unsigned int)hb << 16);
          sacc[ct] += rv;
          qacc[ct] = fmaf(rv, rv, qacc[ct]);
          tpu[w][quad * 4 + i][ct * 16 + col] = hb;
        }
      }
      asm volatile("s_waitcnt lgkmcnt(0)" ::: "memory");

      {
        const int pi = lane >> 2, cc = lane & 3;
        const uint4* tr = (const uint4*)&tpu[w][pi][cc * 16];
        const uint4 a = tr[0];
        const uint4 bq = tr[1];
        unsigned short* zp = z + (size_t)(pbase + pi) * 64 + cc * 16;
        *(uint4*)zp = a;
        *(uint4*)(zp + 8) = bq;
      }
      asm volatile("s_waitcnt lgkmcnt(0)" ::: "memory");
    }
  }

#pragma unroll
  for (int ct = 0; ct < 4; ++ct) {
    float sv = sacc[ct], qv = qacc[ct];
    sv += __shfl_xor(sv, 16);
    sv += __shfl_xor(sv, 32);
    qv += __shfl_xor(qv, 16);
    qv += __shfl_xor(qv, 32);
    if (quad == 0) {
      atomicAdd(&ls[ct * 16 + col], sv);
      atomicAdd(&ls[64 + ct * 16 + col], qv);
    }
  }
  __syncthreads();
  if (t < 128) atomicAdd(&gstats[t], ls[t]);  // s[0..63], q[64..127]
}

// ---------------------------------------------------------------------------
// k_l3 v9 (MFMA, register epilogue, LDS-staged weights): 2048 blocks,
// 2 centers/wave (8 blocks/CU for latency hiding). Logic unchanged.
// ---------------------------------------------------------------------------
__global__ __launch_bounds__(256, 4) void k_l3(
    const unsigned short* __restrict__ zin,
    const unsigned short* __restrict__ wf,
    const float* __restrict__ bias, const float* __restrict__ ss,
    const float* __restrict__ gvec, float* __restrict__ maxz,
    float* __restrict__ gstats)
{
  __shared__ float ls[256];
  __shared__ unsigned short wfl[8192];        // 16 KB fragment table (LDS copy)
  __shared__ float ssl[128];                  // BN2 scale/shift (LDS copy)
  const int t = threadIdx.x;
  const int lane = t & 63;
  const int w = t >> 6;
  const int quad = lane >> 4;
  const int col = lane & 15;

  // stage wf (1024 x uint4 = 16 KB) + ss, zero ls
  {
    const uint4* wsrc = (const uint4*)wf;
    uint4* wdst = (uint4*)wfl;
#pragma unroll
    for (int i = 0; i < 4; ++i) wdst[t + 256 * i] = wsrc[t + 256 * i];
  }
  if (t < 128) ssl[t] = ss[t];
  ls[t] = 0.0f;
  __syncthreads();

  const int c0 = blockIdx.x * 8 + w * 2;      // 2048 blocks, 8 centers each

  const float4* scv = (const float4*)ssl;
  const float4* shv = (const float4*)(ssl + 64);

  // per-lane channel constants: ch(ct) = ct*16+col
  float bo[8];
  bool up[8];
#pragma unroll
  for (int ct = 0; ct < 8; ++ct) {
    bo[ct] = bias[ct * 16 + col];
    up[ct] = (gvec[ct * 16 + col] >= 0.0f);
  }

  float sacc[8], qacc[8];
#pragma unroll
  for (int ct = 0; ct < 8; ++ct) { sacc[ct] = 0.0f; qacc[ct] = 0.0f; }

#pragma unroll 1
  for (int ci = 0; ci < 2; ++ci) {
    const int c = c0 + ci;
    float mx[8];

#pragma unroll 1
    for (int r = 0; r < 2; ++r) {
      const int prow = c * 32 + r * 16 + col;   // this lane's A-row point

      // build A-fragments (ks=0,1): load 16B of z, BN2+ReLU, repack bf16
      bf16x8 afr[2];
#pragma unroll
      for (int ks = 0; ks < 2; ++ks) {
        const int k0 = ks * 32 + quad * 8;
        const uint4 raw = *(const uint4*)(zin + (size_t)prow * 64 + k0);
        const float4 s0 = scv[k0 >> 2], s1 = scv[(k0 >> 2) + 1];
        const float4 h0 = shv[k0 >> 2], h1 = shv[(k0 >> 2) + 1];
        const float f0 = fmaxf(0.0f, fmaf(bf_lo(raw.x), s0.x, h0.x));
        const float f1 = fmaxf(0.0f, fmaf(bf_hi(raw.x), s0.y, h0.y));
        const float f2 = fmaxf(0.0f, fmaf(bf_lo(raw.y), s0.z, h0.z));
        const float f3 = fmaxf(0.0f, fmaf(bf_hi(raw.y), s0.w, h0.w));
        const float f4 = fmaxf(0.0f, fmaf(bf_lo(raw.z), s1.x, h1.x));
        const float f5 = fmaxf(0.0f, fmaf(bf_hi(raw.z), s1.y, h1.y));
        const float f6 = fmaxf(0.0f, fmaf(bf_lo(raw.w), s1.z, h1.z));
        const float f7 = fmaxf(0.0f, fmaf(bf_hi(raw.w), s1.w, h1.w));
        union { uint4 u; bf16x8 v; } cv;
        cv.u.x = pack_bf2(f0, f1);
        cv.u.y = pack_bf2(f2, f3);
        cv.u.z = pack_bf2(f4, f5);
        cv.u.w = pack_bf2(f6, f7);
        afr[ks] = cv.v;
      }

      f32x4 acc[8];
#pragma unroll
      for (int ct = 0; ct < 8; ++ct) acc[ct] = (f32x4){0.f, 0.f, 0.f, 0.f};

#pragma unroll
      for (int ct = 0; ct < 8; ++ct) {
        const bf16x8 b0 = *(const bf16x8*)(wfl + ((ct * 2 + 0) * 64 + lane) * 8);
        const bf16x8 b1 = *(const bf16x8*)(wfl + ((ct * 2 + 1) * 64 + lane) * 8);
        acc[ct] = __builtin_amdgcn_mfma_f32_16x16x32_bf16(afr[0], b0, acc[ct], 0, 0, 0);
        acc[ct] = __builtin_amdgcn_mfma_f32_16x16x32_bf16(afr[1], b1, acc[ct], 0, 0, 0);
      }

      // in-register epilogue: bias, stats, tile-local max
#pragma unroll
      for (int ct = 0; ct < 8; ++ct) {
        const float v0 = acc[ct][0] + bo[ct];
        const float v1 = acc[ct][1] + bo[ct];
        const float v2 = acc[ct][2] + bo[ct];
        const float v3 = acc[ct][3] + bo[ct];
        sacc[ct] += (v0 + v1) + (v2 + v3);
        float qq = fmaf(v0, v0, qacc[ct]);
        qq = fmaf(v1, v1, qq);
        qq = fmaf(v2, v2, qq);
        qacc[ct] = fmaf(v3, v3, qq);
        const float m4 = up[ct]
            ? fmaxf(fmaxf(v0, v1), fmaxf(v2, v3))
            : fminf(fminf(v0, v1), fminf(v2, v3));
        mx[ct] = (r == 0) ? m4
                          : (up[ct] ? fmaxf(mx[ct], m4) : fminf(mx[ct], m4));
      }
    }

    // cross-quad combine (16 pts/quad-slice -> 32 pts) and store
#pragma unroll
    for (int ct = 0; ct < 8; ++ct) {
      float m = mx[ct];
      const float o1 = __shfl_xor(m, 16);
      m = up[ct] ? fmaxf(m, o1) : fminf(m, o1);
      const float o2 = __shfl_xor(m, 32);
      m = up[ct] ? fmaxf(m, o2) : fminf(m, o2);
      if (quad == 0) maxz[(size_t)c * 128 + ct * 16 + col] = m;
    }
  }

  // stats: cross-quad reduce, aggregate in LDS, one global atomic per thread
#pragma unroll
  for (int ct = 0; ct < 8; ++ct) {
    float sv = sacc[ct], qv = qacc[ct];
    sv += __shfl_xor(sv, 16);
    sv += __shfl_xor(sv, 32);
    qv += __shfl_xor(qv, 16);
    qv += __shfl_xor(qv, 32);
    if (quad == 0) {
      atomicAdd(&ls[ct * 16 + col], sv);
      atomicAdd(&ls[128 + ct * 16 + col], qv);
    }
  }
  __syncthreads();
  atomicAdd(&gstats[t], ls[t]);              // 256 slots: s[0..127], q[128..255]
}

// ---------------------------------------------------------------------------
// k_bnfin: scale = g*rsqrt(var+eps), shift = be - mu*scale  (64 channels)
// ---------------------------------------------------------------------------
__global__ void k_bnfin(const float* __restrict__ gstats,
                        const float* __restrict__ g, const float* __restrict__ be,
                        float* __restrict__ ss)
{
  const int t = threadIdx.x;  // 64
  const float s = gstats[t], q = gstats[64 + t];
  const float mu = s * NTINV;
  const float var = q * NTINV - mu * mu;
  const float scale = g[t] * rsqrtf(var + BN_EPS);
  ss[t] = scale;
  ss[64 + t] = be[t] - mu * scale;
}

// ---------------------------------------------------------------------------
// k_final: finalize BN3, apply to pooled extremes, ReLU, transpose to (B,128,M)
// gstats layout here: s at [ch], q at [128+ch].
// ---------------------------------------------------------------------------
__global__ __launch_bounds__(256) void k_final(
    const float* __restrict__ maxz, const float* __restrict__ gstats,
    const float* __restrict__ g, const float* __restrict__ be,
    float* __restrict__ out)
{
  __shared__ float sc[128], sh[128];
  __shared__ float tile[128][65];
  const int t = threadIdx.x;
  const int b = blockIdx.x >> 5;
  const int m0 = (blockIdx.x & 31) * 64;
  if (t < 128) {
    const float s = gstats[t], q = gstats[128 + t];
    const float mu = s * NTINV;
    const float var = q * NTINV - mu * mu;
    const float scale = g[t] * rsqrtf(var + BN_EPS);
    sc[t] = scale;
    sh[t] = be[t] - mu * scale;
  }
  __syncthreads();
  const float* src = maxz + (size_t)(b * M_ + m0) * 128;
#pragma unroll
  for (int r = 0; r < 8; ++r) {
    const int flat = r * 1024 + t * 4;
    const int ml = flat >> 7;
    const int o = flat & 127;
    const float4 v = *(const float4*)(src + flat);
    tile[o + 0][ml] = fmaxf(0.0f, fmaf(v.x, sc[o + 0], sh[o + 0]));
    tile[o + 1][ml] = fmaxf(0.0f, fmaf(v.y, sc[o + 1], sh[o + 1]));
    tile[o + 2][ml] = fmaxf(0.0f, fmaf(v.z, sc[o + 2], sh[o + 2]));
    tile[o + 3][ml] = fmaxf(0.0f, fmaf(v.w, sc[o + 3], sh[o + 3]));
  }
  __syncthreads();
  const int o = t >> 1;
  const int mh = (t & 1) * 32;
  float* dst = out + B_ * M_ * 3 + (size_t)(b * 128 + o) * M_ + m0 + mh;
#pragma unroll
  for (int q = 0; q < 8; ++q) {
    float4 v;
    v.x = tile[o][mh + q * 4 + 0];
    v.y = tile[o][mh + q * 4 + 1];
    v.z = tile[o][mh + q * 4 + 2];
    v.w = tile[o][mh + q * 4 + 3];
    *(float4*)(dst + q * 4) = v;
  }
}

// ---------------------------------------------------------------------------
extern "C" void kernel_launch(void* const* d_in, const int* in_sizes, int n_in,
                              void* d_out, int out_size, void* d_ws, size_t ws_size,
                              hipStream_t stream) {
  (void)in_sizes; (void)n_in; (void)out_size;
  if (ws_size < WS_NEED) return;  // safety: fail cleanly, not with a memfault

  const float* xyz = (const float*)d_in[0];
  const float* feat = (const float*)d_in[1];
  const float* W1 = (const float*)d_in[2];
  const float* b1 = (const float*)d_in[3];
  const float* g1 = (const float*)d_in[4];
  const float* be1 = (const float*)d_in[5];
  const float* W2 = (const float*)d_in[6];
  const float* b2 = (const float*)d_in[7];
  const float* g2 = (const float*)d_in[8];
  const float* be2 = (const float*)d_in[9];
  const float* W3 = (const float*)d_in[10];
  const float* b3 = (const float*)d_in[11];
  const float* g3 = (const float*)d_in[12];
  const float* be3 = (const float*)d_in[13];
  float* out = (float*)d_out;
  char* ws = (char*)d_ws;

  int* knn = (int*)(ws + OFF_KNN);
  unsigned short* featB = (unsigned short*)(ws + OFF_FEATB);
  float* maxz = (float*)(ws + OFF_MAXZ);     // aliases featB (dead after k_l1)
  float* xyz4 = (float*)(ws + OFF_XYZ4);
  float* xn = (float*)(ws + OFF_XN);
  float* wt1 = (float*)(ws + OFF_WT1);
  float* wt2 = (float*)(ws + OFF_WT2);
  unsigned short* wt3f = (unsigned short*)(ws + OFF_WT3);
  unsigned short* w1f = (unsigned short*)(ws + OFF_W1F);
  unsigned short* w2f = (unsigned short*)(ws + OFF_W2F);
  float* gst = (float*)(ws + OFF_GST);
  float* ss1 = (float*)(ws + OFF_SS1);
  float* ss2 = (float*)(ws + OFF_SS2);
  unsigned short* z = (unsigned short*)(ws + OFF_Z);

  hipMemsetAsync(gst, 0, 512 * sizeof(float), stream);
  k_prep<<<385, 256, 0, stream>>>(xyz, feat, W1, W2, W3, featB, xyz4, xn,
                                  wt1, wt2, wt3f, w1f, w2f, out);
  k_knn<<<4096, 256, 0, stream>>>(xyz, xyz4, knn);
  k_l1<<<2048, 256, 0, stream>>>(xyz4, featB, knn, out, wt1, b1, w1f, z, gst);
  k_bnfin<<<1, 64, 0, stream>>>(gst, g1, be1, ss1);
  k_l2<<<2048, 256, 0, stream>>>(z, w2f, b2, ss1, gst + 128);
  k_bnfin<<<1, 64, 0, stream>>>(gst + 128, g2, be2, ss2);
  k_l3<<<2048, 256, 0, stream>>>(z, wt3f, b3, ss2, g3, maxz, gst + 256);
  k_final<<<256, 256, 0, stream>>>(maxz, gst + 256, g3, be3, out);
}

// Round 12
// 379.606 us; speedup vs baseline: 1.1804x; 1.1804x over previous
//
#include <hip/hip_runtime.h>
#include <cstdint>

// ---------------------------------------------------------------------------
// SA_Layer_PN2: centers + 32-NN + (gather,concat) -> 3x [1x1conv -> BN -> ReLU]
// -> max over k.  f32 math, bf16 activation storage.
// R22 (383us, PASS) = baseline. R23 regressed (block split). R24 FAILED:
// k_knn 8-center restructure changed d2key contraction -> rank-32 flips.
// LESSON: k_knn selection is codegen-fragile; R19 form (4 centers/block,
// scalar locals, 4096 blocks) is FROZEN — structure, grid, and key math.
// R25 (this file): R22 state + two correctness-safe changes only:
//  (1) BN-finalize inlined into k_l2/k_l3 prologues (bit-exact k_bnfin
//      formula from gstats; ss bitwise identical) — removes 2 launches.
//  (2) k_l1 prefetches knn/xyz4 for both r-tiles per center (load reorder
//      only; values identical) — breaks gather dependency chain.
// d2key expression UNCHANGED (verified contract — do not touch).
// ---------------------------------------------------------------------------

constexpr int B_ = 8;
constexpr int N_ = 8192;
constexpr int M_ = 2048;
constexpr int K_ = 32;
constexpr float NTINV = 1.0f / 524288.0f;   // 1 / (B*M*K)
constexpr float BN_EPS = 1e-5f;

// workspace layout (bytes)
constexpr size_t OFF_KNN   = 0;             // int32 [B*M*K]          2,097,152
constexpr size_t OFF_FEATB = 2097152;       // bf16 [B*N*64]          8,388,608
constexpr size_t OFF_MAXZ  = 2097152;       // f32 [16384*128] ALIASES featB (dead after k_l1)
constexpr size_t OFF_XYZ4  = 10485760;      // f32x4 [B*N]            2,097,152
constexpr size_t OFF_XN    = 12582912;      // f32 [B*N]                262,144
constexpr size_t OFF_WT1   = 12845056;      // f32 [67*64]               17,152
constexpr size_t OFF_WT2   = 12862208;      // f32 [64*64]               16,384
constexpr size_t OFF_WT3   = 12878592;      // bf16 frags [8192]         16,384
constexpr size_t OFF_W1F   = 12894976;      // bf16 frags [4096]          8,192
constexpr size_t OFF_W2F   = 12903168;      // bf16 frags [4096]          8,192
constexpr size_t OFF_GST   = 12911360;      // f32 [512]
constexpr size_t OFF_SS1   = 12913408;      // f32 [128]  (unused now)
constexpr size_t OFF_SS2   = 12913920;      // f32 [128]  (unused now)
constexpr size_t OFF_Z     = 12914432;      // bf16 [524288*64]      67,108,864
constexpr size_t WS_NEED   = 80023296;      // ~80 MB total

typedef __attribute__((ext_vector_type(8))) short bf16x8;
typedef __attribute__((ext_vector_type(4))) float f32x4;

// ---- bf16 helpers (RNE) ----------------------------------------------------
__device__ __forceinline__ unsigned int pack_bf2(float a, float b) {
  unsigned int ua = __float_as_uint(a);
  unsigned int ub = __float_as_uint(b);
  ua = ua + 0x7FFFu + ((ua >> 16) & 1u);
  ub = ub + 0x7FFFu + ((ub >> 16) & 1u);
  return (ua >> 16) | (ub & 0xFFFF0000u);
}
__device__ __forceinline__ float bf_lo(unsigned int u) { return __uint_as_float(u << 16); }
__device__ __forceinline__ float bf_hi(unsigned int u) { return __uint_as_float(u & 0xFFFF0000u); }
// value as it will appear after bf16 store+reload (same arithmetic as pack_bf2)
__device__ __forceinline__ float bf_round(float x) {
  unsigned int u = __float_as_uint(x);
  u = (u + 0x7FFFu + ((u >> 16) & 1u)) & 0xFFFF0000u;
  return __uint_as_float(u);
}

// monotone key — VERIFIED expression (R2/R14/R18). Single inlined definition
// => identical lowering at every call site (pass1/pass2/fallback consistent).
__device__ __forceinline__ unsigned int d2key(const float4 pv, float cx, float cy,
                                              float cz, float cb) {
  const float dot = cx * pv.x + cy * pv.y + cz * pv.z;
  const float d2 = (cb + pv.w) - 2.0f * dot;          // same formula as ref
  const unsigned int bits = __float_as_uint(d2);
  return bits ^ ((unsigned int)((int)bits >> 31) | 0x80000000u);
}
__device__ __forceinline__ int cindex(int m) {
  return (int)(((long long)m * (N_ - 1)) / (M_ - 1));
}

// ---------------------------------------------------------------------------
// k_prep: featB (bf16) pack, xyz4 pad (norm in .w), weight transposes,
// centers, + W3/W1(cols 3..66)/W2 packed as MFMA B-fragments.
// ---------------------------------------------------------------------------
__global__ __launch_bounds__(256) void k_prep(
    const float* __restrict__ xyz, const float* __restrict__ feat,
    const float* __restrict__ W1, const float* __restrict__ W2,
    const float* __restrict__ W3,
    unsigned short* __restrict__ featB, float* __restrict__ xyz4,
    float* __restrict__ xn,
    float* __restrict__ wt1, float* __restrict__ wt2,
    unsigned short* __restrict__ wt3f,
    unsigned short* __restrict__ w1f, unsigned short* __restrict__ w2f,
    float* __restrict__ cent_out)
{
  const int id = blockIdx.x * 256 + threadIdx.x;
  if (id < B_ * N_) {
    const int b = id >> 13;
    const int n = id & (N_ - 1);
    const float* pp = xyz + id * 3;
    const float x = pp[0], y = pp[1], z = pp[2];
    const float nrm = x * x + y * y + z * z;
    xn[id] = nrm;
    float4* x4 = (float4*)xyz4;
    x4[id] = make_float4(x, y, z, nrm);
    const float* fsrc = feat + b * 64 * N_ + n;
    unsigned short* fdst = featB + (size_t)id * 64;
#pragma unroll
    for (int c8 = 0; c8 < 8; ++c8) {
      uint4 v;
      v.x = pack_bf2(fsrc[(c8 * 8 + 0) * N_], fsrc[(c8 * 8 + 1) * N_]);
      v.y = pack_bf2(fsrc[(c8 * 8 + 2) * N_], fsrc[(c8 * 8 + 3) * N_]);
      v.z = pack_bf2(fsrc[(c8 * 8 + 4) * N_], fsrc[(c8 * 8 + 5) * N_]);
      v.w = pack_bf2(fsrc[(c8 * 8 + 6) * N_], fsrc[(c8 * 8 + 7) * N_]);
      *(uint4*)(fdst + c8 * 8) = v;
    }
  } else if (id < B_ * N_ + B_ * M_) {
    const int idx = id - B_ * N_;
    const int b = idx >> 11;
    const int m = idx & (M_ - 1);
    const int ic = cindex(m);
    const float* cp = xyz + (b * N_ + ic) * 3;
    float* dst = cent_out + idx * 3;
    dst[0] = cp[0]; dst[1] = cp[1]; dst[2] = cp[2];
  } else if (id < 81920 + 4288) {
    const int i = id - 81920;
    const int c = i >> 6, o = i & 63;
    wt1[i] = W1[o * 67 + c];
  } else if (id < 86208 + 4096) {
    const int i = id - 86208;
    const int c = i >> 6, o = i & 63;
    wt2[c * 64 + o] = W2[o * 64 + c];
  } else if (id < 90304 + 1024) {
    const int f = id - 90304;           // f = (ct*2+ks)*64 + lane, ct 0..7
    const int ct = f >> 7;
    const int ks = (f >> 6) & 1;
    const int lane = f & 63;
    const int quad = lane >> 4;
    const int col = lane & 15;
    const int n = ct * 16 + col;
    const int kb = ks * 32 + quad * 8;
    const float* wr = W3 + n * 64 + kb;
    uint4 v;
    v.x = pack_bf2(wr[0], wr[1]);
    v.y = pack_bf2(wr[2], wr[3]);
    v.z = pack_bf2(wr[4], wr[5]);
    v.w = pack_bf2(wr[6], wr[7]);
    ((uint4*)wt3f)[f] = v;
  } else if (id < 91328 + 512) {
    const int f = id - 91328;           // W2 fragments: ct 0..3
    const int ct = f >> 7;
    const int ks = (f >> 6) & 1;
    const int lane = f & 63;
    const int quad = lane >> 4;
    const int col = lane & 15;
    const int n = ct * 16 + col;
    const int kb = ks * 32 + quad * 8;
    const float* wr = W2 + n * 64 + kb;
    uint4 v;
    v.x = pack_bf2(wr[0], wr[1]);
    v.y = pack_bf2(wr[2], wr[3]);
    v.z = pack_bf2(wr[4], wr[5]);
    v.w = pack_bf2(wr[6], wr[7]);
    ((uint4*)w2f)[f] = v;
  } else if (id < 91840 + 512) {
    const int f = id - 91840;           // W1 fragments (input cols 3..66)
    const int ct = f >> 7;
    const int ks = (f >> 6) & 1;
    const int lane = f & 63;
    const int quad = lane >> 4;
    const int col = lane & 15;
    const int n = ct * 16 + col;
    const int kb = ks * 32 + quad * 8;
    const float* wr = W1 + n * 67 + 3 + kb;
    uint4 v;
    v.x = pack_bf2(wr[0], wr[1]);
    v.y = pack_bf2(wr[2], wr[3]);
    v.z = pack_bf2(wr[4], wr[5]);
    v.w = pack_bf2(wr[6], wr[7]);
    ((uint4*)w1f)[f] = v;
  }
}

// ---------------------------------------------------------------------------
// k_knn R19: one block = 4 centers. Occupancy-tuned. FROZEN (structure,
// grid 4096, scalar-local key math — codegen-sensitive, do not restructure).
// ---------------------------------------------------------------------------
__global__ __launch_bounds__(256, 4) void k_knn(
    const float* __restrict__ xyz, const float* __restrict__ xyz4,
    int* __restrict__ knn)
{
  __shared__ unsigned int hist4[4][1024];       // 16 KB; reused as keys2[4][512]
  __shared__ int sh_cnt[4], sh_B4[4], wsum4[4][4];
  __shared__ unsigned long long wbest[4];

  unsigned long long* keys2 = (unsigned long long*)hist4;

  const int t = threadIdx.x;
  const int lane = t & 63;
  const int w = t >> 6;
  const int bid = blockIdx.x;
  const int b = bid >> 9;
  const int m0 = (bid & 511) * 4;
  const int row_base = (b * M_ + m0) * K_;
  const float4* pts = ((const float4*)xyz4) + b * N_;

  // centers (block-uniform scalar loads)
  const float* cp0 = xyz + (b * N_ + cindex(m0 + 0)) * 3;
  const float* cp1 = xyz + (b * N_ + cindex(m0 + 1)) * 3;
  const float* cp2 = xyz + (b * N_ + cindex(m0 + 2)) * 3;
  const float* cp3 = xyz + (b * N_ + cindex(m0 + 3)) * 3;
  const float cx0 = cp0[0], cy0 = cp0[1], cz0 = cp0[2];
  const float cx1 = cp1[0], cy1 = cp1[1], cz1 = cp1[2];
  const float cx2 = cp2[0], cy2 = cp2[1], cz2 = cp2[2];
  const float cx3 = cp3[0], cy3 = cp3[1], cz3 = cp3[2];
  const float cb0 = cx0 * cx0 + cy0 * cy0 + cz0 * cz0;
  const float cb1 = cx1 * cx1 + cy1 * cy1 + cz1 * cz1;
  const float cb2 = cx2 * cx2 + cy2 * cy2 + cz2 * cz2;
  const float cb3 = cx3 * cx3 + cy3 * cy3 + cz3 * cz3;

  // zero hist (16 KB) + counters
  {
    uint4* hz = (uint4*)hist4;
    const uint4 z4 = make_uint4(0u, 0u, 0u, 0u);
#pragma unroll
    for (int i = 0; i < 4; ++i) hz[t * 4 + i] = z4;
  }
  if (t < 4) sh_cnt[t] = 0;
  __syncthreads();

  // ---- pass 1: stream points once (batch-8 chunks), 4 running minima ----
  unsigned int um0 = 0xFFFFFFFFu, um1 = 0xFFFFFFFFu;
  unsigned int um2 = 0xFFFFFFFFu, um3 = 0xFFFFFFFFu;
#pragma unroll 1
  for (int jo = 0; jo < 4; ++jo) {
    float4 pv8[8];
#pragma unroll
    for (int ji = 0; ji < 8; ++ji) pv8[ji] = pts[t + 256 * (jo * 8 + ji)];
#pragma unroll
    for (int ji = 0; ji < 8; ++ji) {
      const float4 pv = pv8[ji];
      const unsigned int k0 = d2key(pv, cx0, cy0, cz0, cb0);
      const unsigned int k1 = d2key(pv, cx1, cy1, cz1, cb1);
      const unsigned int k2 = d2key(pv, cx2, cy2, cz2, cb2);
      const unsigned int k3 = d2key(pv, cx3, cy3, cz3, cb3);
      um0 = um0 < k0 ? um0 : k0;
      um1 = um1 < k1 ? um1 : k1;
      um2 = um2 < k2 ? um2 : k2;
      um3 = um3 < k3 ? um3 : k3;
    }
  }
  atomicAdd(&hist4[0][um0 >> 22], 1u);
  atomicAdd(&hist4[1][um1 >> 22], 1u);
  atomicAdd(&hist4[2][um2 >> 22], 1u);
  atomicAdd(&hist4[3][um3 >> 22], 1u);
  __syncthreads();

  // ---- fused 4 scans: thread t owns slots [4t, 4t+4) of each hist4[s] ----
  {
    unsigned int h4[4][4], incl[4], sum[4];
#pragma unroll
    for (int s = 0; s < 4; ++s) {
      const uint4 ha = ((const uint4*)&hist4[s][0])[t];
      h4[s][0] = ha.x; h4[s][1] = ha.y; h4[s][2] = ha.z; h4[s][3] = ha.w;
      sum[s] = ha.x + ha.y + ha.z + ha.w;
      incl[s] = sum[s];
    }
#pragma unroll
    for (int off = 1; off < 64; off <<= 1) {
#pragma unroll
      for (int s = 0; s < 4; ++s) {
        const unsigned int v = __shfl_up(incl[s], off);
        if (lane >= off) incl[s] += v;
      }
    }
    if (lane == 63) {
#pragma unroll
      for (int s = 0; s < 4; ++s) wsum4[s][w] = (int)incl[s];
    }
    __syncthreads();
#pragma unroll
    for (int s = 0; s < 4; ++s) {
      unsigned int wpre = 0;
#pragma unroll
      for (int i = 0; i < 4; ++i) wpre += (i < w) ? (unsigned int)wsum4[s][i] : 0u;
      const unsigned int excl = wpre + incl[s] - sum[s];   // minima in slots < 4t
      unsigned int run = excl;
      int Bq = -1;
#pragma unroll
      for (int q = 0; q < 4; ++q) { run += h4[s][q]; if (Bq < 0 && run >= 33) Bq = t * 4 + q; }
      if (Bq >= 0 && excl < 33) sh_B4[s] = Bq;             // unique crossing thread
    }
    __syncthreads();                                       // sh_B4 visible
  }

  const unsigned int Bb0 = (unsigned int)sh_B4[0];
  const unsigned int Bb1 = (unsigned int)sh_B4[1];
  const unsigned int Bb2 = (unsigned int)sh_B4[2];
  const unsigned int Bb3 = (unsigned int)sh_B4[3];

  // ---- pass 2: stream once more (batch-8), compact candidates ----
#pragma unroll 1
  for (int jo = 0; jo < 4; ++jo) {
    float4 pv8[8];
#pragma unroll
    for (int ji = 0; ji < 8; ++ji) pv8[ji] = pts[t + 256 * (jo * 8 + ji)];
#pragma unroll
    for (int ji = 0; ji < 8; ++ji) {
      const float4 pv = pv8[ji];
      const unsigned int idx = (unsigned int)(t + 256 * (jo * 8 + ji));
      const unsigned int k0 = d2key(pv, cx0, cy0, cz0, cb0);
      const unsigned int k1 = d2key(pv, cx1, cy1, cz1, cb1);
      const unsigned int k2 = d2key(pv, cx2, cy2, cz2, cb2);
      const unsigned int k3 = d2key(pv, cx3, cy3, cz3, cb3);
      if ((k0 >> 22) <= Bb0) {
        const int pos = atomicAdd(&sh_cnt[0], 1);
        if (pos < 512) keys2[0 * 512 + pos] = ((unsigned long long)k0 << 32) | idx;
      }
      if ((k1 >> 22) <= Bb1) {
        const int pos = atomicAdd(&sh_cnt[1], 1);
        if (pos < 512) keys2[1 * 512 + pos] = ((unsigned long long)k1 << 32) | idx;
      }
      if ((k2 >> 22) <= Bb2) {
        const int pos = atomicAdd(&sh_cnt[2], 1);
        if (pos < 512) keys2[2 * 512 + pos] = ((unsigned long long)k2 << 32) | idx;
      }
      if ((k3 >> 22) <= Bb3) {
        const int pos = atomicAdd(&sh_cnt[3], 1);
        if (pos < 512) keys2[3 * 512 + pos] = ((unsigned long long)k3 << 32) | idx;
      }
    }
  }
  __syncthreads();

  // ---- rank: wave w ranks center w (exact 64-bit rank, broadcast reads) ----
  {
    const int C = sh_cnt[w];
    if (C <= 512) {
      const unsigned long long* kk = keys2 + w * 512;
      int* row = knn + row_base + w * K_;
      for (int i = lane; i < C; i += 64) {
        const unsigned long long k = kk[i];
        int r = 0;
        for (int q = 0; q < C; ++q) r += (kk[q] < k) ? 1 : 0;
        if (r < K_) row[r] = (int)(k & 0xFFFFFFFFull);
      }
    }
  }
  __syncthreads();

  // ---- fallback (practically never): exact 32-round extraction ----
#pragma unroll
  for (int s = 0; s < 4; ++s) {
    if (sh_cnt[s] > 512) {                         // block-uniform
      const float cx = (s == 0) ? cx0 : (s == 1) ? cx1 : (s == 2) ? cx2 : cx3;
      const float cy = (s == 0) ? cy0 : (s == 1) ? cy1 : (s == 2) ? cy2 : cy3;
      const float cz = (s == 0) ? cz0 : (s == 1) ? cz1 : (s == 2) ? cz2 : cz3;
      const float cb = (s == 0) ? cb0 : (s == 1) ? cb1 : (s == 2) ? cb2 : cb3;
      unsigned int uu[32];
#pragma unroll
      for (int j = 0; j < 32; ++j) uu[j] = d2key(pts[t + 256 * j], cx, cy, cz, cb);
      int* row = knn + row_base + s * K_;
#pragma unroll 1
      for (int r = 0; r < K_; ++r) {
        unsigned long long best = 0xFFFFFFFFFFFFFFFFull;
#pragma unroll
        for (int j = 0; j < 32; ++j) {
          unsigned long long k = ((unsigned long long)uu[j] << 32) | (unsigned int)(t + 256 * j);
          best = (k < best) ? k : best;
        }
#pragma unroll
        for (int off = 1; off < 64; off <<= 1) {
          unsigned long long o = __shfl_xor(best, off);
          best = (o < best) ? o : best;
        }
        if (lane == 0) wbest[w] = best;
        __syncthreads();
        unsigned long long b01 = wbest[0] < wbest[1] ? wbest[0] : wbest[1];
        unsigned long long b23 = wbest[2] < wbest[3] ? wbest[2] : wbest[3];
        best = b01 < b23 ? b01 : b23;
        if (t == 0) row[r] = (int)(best & 0xFFFFFFFFull);
        const int n_match = (int)(best & 0xFFFFFFFFull);
#pragma unroll
        for (int j = 0; j < 32; ++j)
          if ((t + 256 * j) == n_match) uu[j] = 0xFFFFFFFFu;
        __syncthreads();
      }
    }
  }
}

// ---------------------------------------------------------------------------
// k_l1 v5b (MFMA, R22-verified + safe gather prefetch): wave owns 4 groups
// of 32 pts (2 r-tiles). A-frag = gathered featB row (bf16 direct). B-frag
// = w1f. knn/xyz4 for both r-tiles prefetched per center (load reorder only).
// Epilogue adds f32 local-xyz x W1[:,0:3] + b1, bf16-rounds, fused layer-1
// stats, per-wave LDS transpose tile [16][68] (no barriers).
// ---------------------------------------------------------------------------
__global__ __launch_bounds__(256, 4) void k_l1(
    const float* __restrict__ xyz4, const unsigned short* __restrict__ featB,
    const int* __restrict__ knn, const float* __restrict__ centers,
    const float* __restrict__ wt1, const float* __restrict__ bias,
    const unsigned short* __restrict__ w1f,
    unsigned short* __restrict__ zout, float* __restrict__ gstats)
{
  __shared__ unsigned short wfl[4096];        // 8 KB W1 fragments
  __shared__ float tp[4][16][68];             // per-wave transpose tiles
  __shared__ float ls[128];
  const int t = threadIdx.x;
  const int lane = t & 63;
  const int w = t >> 6;
  const int quad = lane >> 4;
  const int col = lane & 15;

  {
    const uint4* src = (const uint4*)w1f;
    uint4* dst = (uint4*)wfl;
    dst[t] = src[t];
    dst[t + 256] = src[t + 256];
  }
  if (t < 128) ls[t] = 0.0f;
  __syncthreads();

  // per-lane channel consts: ch = ct*16+col
  float w1x[4], w1y[4], w1z[4], b14[4];
#pragma unroll
  for (int ct = 0; ct < 4; ++ct) {
    const int ch = ct * 16 + col;
    w1x[ct] = wt1[ch];
    w1y[ct] = wt1[64 + ch];
    w1z[ct] = wt1[128 + ch];
    b14[ct] = bias[ch];
  }

  float sacc[4] = {0.f, 0.f, 0.f, 0.f};
  float qacc[4] = {0.f, 0.f, 0.f, 0.f};

  const int c0 = blockIdx.x * 16 + w * 4;     // 1024 blocks, 16 centers each

#pragma unroll 1
  for (int ci = 0; ci < 4; ++ci) {
    const int c = c0 + ci;                    // global center id
    const int b = c >> 11;
    const float* cp = centers + c * 3;        // wave-uniform
    const float cx = cp[0], cy = cp[1], cz = cp[2];

    // prefetch both r-tiles' gather state (load reorder only; values same)
    const int nnA = knn[c * 32 + col];
    const int nnB = knn[c * 32 + 16 + col];
    const float4 pvA = ((const float4*)xyz4)[b * N_ + nnA];
    const float4 pvB = ((const float4*)xyz4)[b * N_ + nnB];

#pragma unroll 1
    for (int rt = 0; rt < 2; ++rt) {
      const int pbase = c * 32 + rt * 16;
      const int nn = rt ? nnB : nnA;
      const float4 pv = rt ? pvB : pvA;
      const size_t frow = ((size_t)b * N_ + nn) * 64;
      const float l0 = pv.x - cx;
      const float l1 = pv.y - cy;
      const float l2 = pv.z - cz;

      bf16x8 afr[2];
#pragma unroll
      for (int ks = 0; ks < 2; ++ks) {
        union { uint4 u; bf16x8 v; } cv;
        cv.u = *(const uint4*)(featB + frow + ks * 32 + quad * 8);
        afr[ks] = cv.v;
      }

      f32x4 acc[4];
#pragma unroll
      for (int ct = 0; ct < 4; ++ct) acc[ct] = (f32x4){0.f, 0.f, 0.f, 0.f};
#pragma unroll
      for (int ct = 0; ct < 4; ++ct) {
        const bf16x8 b0 = *(const bf16x8*)(wfl + ((ct * 2 + 0) * 64 + lane) * 8);
        const bf16x8 b1 = *(const bf16x8*)(wfl + ((ct * 2 + 1) * 64 + lane) * 8);
        acc[ct] = __builtin_amdgcn_mfma_f32_16x16x32_bf16(afr[0], b0, acc[ct], 0, 0, 0);
        acc[ct] = __builtin_amdgcn_mfma_f32_16x16x32_bf16(afr[1], b1, acc[ct], 0, 0, 0);
      }

      // epilogue: + local_xyz part (f32) + bias, round, stats, LDS tile
#pragma unroll
      for (int i = 0; i < 4; ++i) {
        const int srcl = quad * 4 + i;        // D point row = quad*4+i
        const float lx = __shfl(l0, srcl);
        const float ly = __shfl(l1, srcl);
        const float lz = __shfl(l2, srcl);
#pragma unroll
        for (int ct = 0; ct < 4; ++ct) {
          const float v = fmaf(lx, w1x[ct],
                          fmaf(ly, w1y[ct],
                          fmaf(lz, w1z[ct], b14[ct]))) + acc[ct][i];
          const float rv = bf_round(v);
          sacc[ct] += rv;
          qacc[ct] = fmaf(rv, rv, qacc[ct]);
          tp[w][quad * 4 + i][ct * 16 + col] = rv;
        }
      }
      asm volatile("s_waitcnt lgkmcnt(0)" ::: "memory");

      // transpose store: lane -> point (lane>>2), channel chunk (lane&3)*16
      {
        const int pi = lane >> 2, cc = lane & 3;
        const float* tr = &tp[w][pi][cc * 16];
        unsigned int o[8];
#pragma unroll
        for (int j = 0; j < 8; ++j) o[j] = pack_bf2(tr[2 * j], tr[2 * j + 1]);
        unsigned short* zp = zout + (size_t)(pbase + pi) * 64 + cc * 16;
        *(uint4*)zp = make_uint4(o[0], o[1], o[2], o[3]);
        *(uint4*)(zp + 8) = make_uint4(o[4], o[5], o[6], o[7]);
      }
      asm volatile("s_waitcnt lgkmcnt(0)" ::: "memory");
    }
  }

  // fused layer-1 stats: channel ct*16+col replicated across quads
#pragma unroll
  for (int ct = 0; ct < 4; ++ct) {
    float sv = sacc[ct], qv = qacc[ct];
    sv += __shfl_xor(sv, 16);
    sv += __shfl_xor(sv, 32);
    qv += __shfl_xor(qv, 16);
    qv += __shfl_xor(qv, 32);
    if (quad == 0) {
      atomicAdd(&ls[ct * 16 + col], sv);
      atomicAdd(&ls[64 + ct * 16 + col], qv);
    }
  }
  __syncthreads();
  if (t < 128) atomicAdd(&gstats[t], ls[t]);  // s[0..63], q[64..127]
}

// ---------------------------------------------------------------------------
// k_l2 v2b (MFMA, in-place, fused layer-2 stats, inlined BN1-finalize):
// block prologue computes ss1 from gstats (bit-exact k_bnfin formula).
// A-frag = z row + BN1/ReLU; B-frag = w2f. Epilogue: +b2, round, stats,
// per-wave LDS transpose, coalesced in-place z store.
// ---------------------------------------------------------------------------
__global__ __launch_bounds__(256, 4) void k_l2(
    unsigned short* __restrict__ z, const unsigned short* __restrict__ w2f,
    const float* __restrict__ bias,
    const float* __restrict__ gst_in, const float* __restrict__ g,
    const float* __restrict__ be,
    float* __restrict__ gstats)
{
  __shared__ unsigned short wfl[4096];        // 8 KB W2 fragments
  __shared__ float tp[4][16][68];
  __shared__ float ls[128];
  __shared__ float ssl[128];
  const int t = threadIdx.x;
  const int lane = t & 63;
  const int w = t >> 6;
  const int quad = lane >> 4;
  const int col = lane & 15;

  {
    const uint4* src = (const uint4*)w2f;
    uint4* dst = (uint4*)wfl;
    dst[t] = src[t];
    dst[t + 256] = src[t + 256];
  }
  if (t < 64) {                               // inlined k_bnfin (bit-exact)
    const float s = gst_in[t], q = gst_in[64 + t];
    const float mu = s * NTINV;
    const float var = q * NTINV - mu * mu;
    const float scale = g[t] * rsqrtf(var + BN_EPS);
    ssl[t] = scale;
    ssl[64 + t] = be[t] - mu * scale;
  }
  if (t < 128) ls[t] = 0.0f;
  __syncthreads();

  const float4* scv = (const float4*)ssl;
  const float4* shv = (const float4*)(ssl + 64);

  float b24[4];
#pragma unroll
  for (int ct = 0; ct < 4; ++ct) b24[ct] = bias[ct * 16 + col];

  float sacc[4] = {0.f, 0.f, 0.f, 0.f};
  float qacc[4] = {0.f, 0.f, 0.f, 0.f};

  const int c0 = blockIdx.x * 16 + w * 4;

#pragma unroll 1
  for (int ci = 0; ci < 4; ++ci) {
    const int c = c0 + ci;
#pragma unroll 1
    for (int rt = 0; rt < 2; ++rt) {
      const int pbase = c * 32 + rt * 16;
      const int prow = pbase + col;

      // A-build: load 16B of z, BN1+ReLU, repack bf16 (k_l3 pattern)
      bf16x8 afr[2];
#pragma unroll
      for (int ks = 0; ks < 2; ++ks) {
        const int k0 = ks * 32 + quad * 8;
        const uint4 raw = *(const uint4*)(z + (size_t)prow * 64 + k0);
        const float4 s0 = scv[k0 >> 2], s1 = scv[(k0 >> 2) + 1];
        const float4 h0 = shv[k0 >> 2], h1 = shv[(k0 >> 2) + 1];
        const float f0 = fmaxf(0.0f, fmaf(bf_lo(raw.x), s0.x, h0.x));
        const float f1 = fmaxf(0.0f, fmaf(bf_hi(raw.x), s0.y, h0.y));
        const float f2 = fmaxf(0.0f, fmaf(bf_lo(raw.y), s0.z, h0.z));
        const float f3 = fmaxf(0.0f, fmaf(bf_hi(raw.y), s0.w, h0.w));
        const float f4 = fmaxf(0.0f, fmaf(bf_lo(raw.z), s1.x, h1.x));
        const float f5 = fmaxf(0.0f, fmaf(bf_hi(raw.z), s1.y, h1.y));
        const float f6 = fmaxf(0.0f, fmaf(bf_lo(raw.w), s1.z, h1.z));
        const float f7 = fmaxf(0.0f, fmaf(bf_hi(raw.w), s1.w, h1.w));
        union { uint4 u; bf16x8 v; } cv;
        cv.u.x = pack_bf2(f0, f1);
        cv.u.y = pack_bf2(f2, f3);
        cv.u.z = pack_bf2(f4, f5);
        cv.u.w = pack_bf2(f6, f7);
        afr[ks] = cv.v;
      }

      f32x4 acc[4];
#pragma unroll
      for (int ct = 0; ct < 4; ++ct) acc[ct] = (f32x4){0.f, 0.f, 0.f, 0.f};
#pragma unroll
      for (int ct = 0; ct < 4; ++ct) {
        const bf16x8 b0 = *(const bf16x8*)(wfl + ((ct * 2 + 0) * 64 + lane) * 8);
        const bf16x8 b1 = *(const bf16x8*)(wfl + ((ct * 2 + 1) * 64 + lane) * 8);
        acc[ct] = __builtin_amdgcn_mfma_f32_16x16x32_bf16(afr[0], b0, acc[ct], 0, 0, 0);
        acc[ct] = __builtin_amdgcn_mfma_f32_16x16x32_bf16(afr[1], b1, acc[ct], 0, 0, 0);
      }

#pragma unroll
      for (int i = 0; i < 4; ++i) {
#pragma unroll
        for (int ct = 0; ct < 4; ++ct) {
          const float v = acc[ct][i] + b24[ct];
          const float rv = bf_round(v);
          sacc[ct] += rv;
          qacc[ct] = fmaf(rv, rv, qacc[ct]);
          tp[w][quad * 4 + i][ct * 16 + col] = rv;
        }
      }
      asm volatile("s_waitcnt lgkmcnt(0)" ::: "memory");

      {
        const int pi = lane >> 2, cc = lane & 3;
        const float* tr = &tp[w][pi][cc * 16];
        unsigned int o[8];
#pragma unroll
        for (int j = 0; j < 8; ++j) o[j] = pack_bf2(tr[2 * j], tr[2 * j + 1]);
        unsigned short* zp = z + (size_t)(pbase + pi) * 64 + cc * 16;
        *(uint4*)zp = make_uint4(o[0], o[1], o[2], o[3]);
        *(uint4*)(zp + 8) = make_uint4(o[4], o[5], o[6], o[7]);
      }
      asm volatile("s_waitcnt lgkmcnt(0)" ::: "memory");
    }
  }

#pragma unroll
  for (int ct = 0; ct < 4; ++ct) {
    float sv = sacc[ct], qv = qacc[ct];
    sv += __shfl_xor(sv, 16);
    sv += __shfl_xor(sv, 32);
    qv += __shfl_xor(qv, 16);
    qv += __shfl_xor(qv, 32);
    if (quad == 0) {
      atomicAdd(&ls[ct * 16 + col], sv);
      atomicAdd(&ls[64 + ct * 16 + col], qv);
    }
  }
  __syncthreads();
  if (t < 128) atomicAdd(&gstats[t], ls[t]);  // s[0..63], q[64..127]
}

// ---------------------------------------------------------------------------
// k_l3 v8b (MFMA, register epilogue, LDS-staged weights, inlined BN2-
// finalize): block prologue computes ss2 from gstats (bit-exact k_bnfin).
// ---------------------------------------------------------------------------
__global__ __launch_bounds__(256, 4) void k_l3(
    const unsigned short* __restrict__ zin,
    const unsigned short* __restrict__ wf,
    const float* __restrict__ bias,
    const float* __restrict__ gst_in, const float* __restrict__ g2v,
    const float* __restrict__ be2v,
    const float* __restrict__ gvec, float* __restrict__ maxz,
    float* __restrict__ gstats)
{
  __shared__ float ls[256];
  __shared__ unsigned short wfl[8192];        // 16 KB fragment table (LDS copy)
  __shared__ float ssl[128];                  // BN2 scale/shift (computed)
  const int t = threadIdx.x;
  const int lane = t & 63;
  const int w = t >> 6;
  const int quad = lane >> 4;
  const int col = lane & 15;

  // stage wf (1024 x uint4 = 16 KB) + compute ss2, zero ls
  {
    const uint4* wsrc = (const uint4*)wf;
    uint4* wdst = (uint4*)wfl;
#pragma unroll
    for (int i = 0; i < 4; ++i) wdst[t + 256 * i] = wsrc[t + 256 * i];
  }
  if (t < 64) {                               // inlined k_bnfin (bit-exact)
    const float s = gst_in[t], q = gst_in[64 + t];
    const float mu = s * NTINV;
    const float var = q * NTINV - mu * mu;
    const float scale = g2v[t] * rsqrtf(var + BN_EPS);
    ssl[t] = scale;
    ssl[64 + t] = be2v[t] - mu * scale;
  }
  ls[t] = 0.0f;
  __syncthreads();

  const int c0 = blockIdx.x * 16 + w * 4;     // 1024 blocks, 16 centers each

  const float4* scv = (const float4*)ssl;
  const float4* shv = (const float4*)(ssl + 64);

  // per-lane channel constants: ch(ct) = ct*16+col
  float bo[8];
  bool up[8];
#pragma unroll
  for (int ct = 0; ct < 8; ++ct) {
    bo[ct] = bias[ct * 16 + col];
    up[ct] = (gvec[ct * 16 + col] >= 0.0f);
  }

  float sacc[8], qacc[8];
#pragma unroll
  for (int ct = 0; ct < 8; ++ct) { sacc[ct] = 0.0f; qacc[ct] = 0.0f; }

#pragma unroll 1
  for (int ci = 0; ci < 4; ++ci) {
    const int c = c0 + ci;
    float mx[8];

#pragma unroll 1
    for (int r = 0; r < 2; ++r) {
      const int prow = c * 32 + r * 16 + col;   // this lane's A-row point

      // build A-fragments (ks=0,1): load 16B of z, BN2+ReLU, repack bf16
      bf16x8 afr[2];
#pragma unroll
      for (int ks = 0; ks < 2; ++ks) {
        const int k0 = ks * 32 + quad * 8;
        const uint4 raw = *(const uint4*)(zin + (size_t)prow * 64 + k0);
        const float4 s0 = scv[k0 >> 2], s1 = scv[(k0 >> 2) + 1];
        const float4 h0 = shv[k0 >> 2], h1 = shv[(k0 >> 2) + 1];
        const float f0 = fmaxf(0.0f, fmaf(bf_lo(raw.x), s0.x, h0.x));
        const float f1 = fmaxf(0.0f, fmaf(bf_hi(raw.x), s0.y, h0.y));
        const float f2 = fmaxf(0.0f, fmaf(bf_lo(raw.y), s0.z, h0.z));
        const float f3 = fmaxf(0.0f, fmaf(bf_hi(raw.y), s0.w, h0.w));
        const float f4 = fmaxf(0.0f, fmaf(bf_lo(raw.z), s1.x, h1.x));
        const float f5 = fmaxf(0.0f, fmaf(bf_hi(raw.z), s1.y, h1.y));
        const float f6 = fmaxf(0.0f, fmaf(bf_lo(raw.w), s1.z, h1.z));
        const float f7 = fmaxf(0.0f, fmaf(bf_hi(raw.w), s1.w, h1.w));
        union { uint4 u; bf16x8 v; } cv;
        cv.u.x = pack_bf2(f0, f1);
        cv.u.y = pack_bf2(f2, f3);
        cv.u.z = pack_bf2(f4, f5);
        cv.u.w = pack_bf2(f6, f7);
        afr[ks] = cv.v;
      }

      f32x4 acc[8];
#pragma unroll
      for (int ct = 0; ct < 8; ++ct) acc[ct] = (f32x4){0.f, 0.f, 0.f, 0.f};

#pragma unroll
      for (int ct = 0; ct < 8; ++ct) {
        const bf16x8 b0 = *(const bf16x8*)(wfl + ((ct * 2 + 0) * 64 + lane) * 8);
        const bf16x8 b1 = *(const bf16x8*)(wfl + ((ct * 2 + 1) * 64 + lane) * 8);
        acc[ct] = __builtin_amdgcn_mfma_f32_16x16x32_bf16(afr[0], b0, acc[ct], 0, 0, 0);
        acc[ct] = __builtin_amdgcn_mfma_f32_16x16x32_bf16(afr[1], b1, acc[ct], 0, 0, 0);
      }

      // in-register epilogue: bias, stats, tile-local max
#pragma unroll
      for (int ct = 0; ct < 8; ++ct) {
        const float v0 = acc[ct][0] + bo[ct];
        const float v1 = acc[ct][1] + bo[ct];
        const float v2 = acc[ct][2] + bo[ct];
        const float v3 = acc[ct][3] + bo[ct];
        sacc[ct] += (v0 + v1) + (v2 + v3);
        float qq = fmaf(v0, v0, qacc[ct]);
        qq = fmaf(v1, v1, qq);
        qq = fmaf(v2, v2, qq);
        qacc[ct] = fmaf(v3, v3, qq);
        const float m4 = up[ct]
            ? fmaxf(fmaxf(v0, v1), fmaxf(v2, v3))
            : fminf(fminf(v0, v1), fminf(v2, v3));
        mx[ct] = (r == 0) ? m4
                          : (up[ct] ? fmaxf(mx[ct], m4) : fminf(mx[ct], m4));
      }
    }

    // cross-quad combine (16 pts/quad-slice -> 32 pts) and store
#pragma unroll
    for (int ct = 0; ct < 8; ++ct) {
      float m = mx[ct];
      const float o1 = __shfl_xor(m, 16);
      m = up[ct] ? fmaxf(m, o1) : fminf(m, o1);
      const float o2 = __shfl_xor(m, 32);
      m = up[ct] ? fmaxf(m, o2) : fminf(m, o2);
      if (quad == 0) maxz[(size_t)c * 128 + ct * 16 + col] = m;
    }
  }

  // stats: cross-quad reduce, aggregate in LDS, one global atomic per thread
#pragma unroll
  for (int ct = 0; ct < 8; ++ct) {
    float sv = sacc[ct], qv = qacc[ct];
    sv += __shfl_xor(sv, 16);
    sv += __shfl_xor(sv, 32);
    qv += __shfl_xor(qv, 16);
    qv += __shfl_xor(qv, 32);
    if (quad == 0) {
      atomicAdd(&ls[ct * 16 + col], sv);
      atomicAdd(&ls[128 + ct * 16 + col], qv);
    }
  }
  __syncthreads();
  atomicAdd(&gstats[t], ls[t]);              // 256 slots: s[0..127], q[128..255]
}

// ---------------------------------------------------------------------------
// k_final: finalize BN3, apply to pooled extremes, ReLU, transpose to (B,128,M)
// gstats layout here: s at [ch], q at [128+ch].
// ---------------------------------------------------------------------------
__global__ __launch_bounds__(256) void k_final(
    const float* __restrict__ maxz, const float* __restrict__ gstats,
    const float* __restrict__ g, const float* __restrict__ be,
    float* __restrict__ out)
{
  __shared__ float sc[128], sh[128];
  __shared__ float tile[128][65];
  const int t = threadIdx.x;
  const int b = blockIdx.x >> 5;
  const int m0 = (blockIdx.x & 31) * 64;
  if (t < 128) {
    const float s = gstats[t], q = gstats[128 + t];
    const float mu = s * NTINV;
    const float var = q * NTINV - mu * mu;
    const float scale = g[t] * rsqrtf(var + BN_EPS);
    sc[t] = scale;
    sh[t] = be[t] - mu * scale;
  }
  __syncthreads();
  const float* src = maxz + (size_t)(b * M_ + m0) * 128;
#pragma unroll
  for (int r = 0; r < 8; ++r) {
    const int flat = r * 1024 + t * 4;
    const int ml = flat >> 7;
    const int o = flat & 127;
    const float4 v = *(const float4*)(src + flat);
    tile[o + 0][ml] = fmaxf(0.0f, fmaf(v.x, sc[o + 0], sh[o + 0]));
    tile[o + 1][ml] = fmaxf(0.0f, fmaf(v.y, sc[o + 1], sh[o + 1]));
    tile[o + 2][ml] = fmaxf(0.0f, fmaf(v.z, sc[o + 2], sh[o + 2]));
    tile[o + 3][ml] = fmaxf(0.0f, fmaf(v.w, sc[o + 3], sh[o + 3]));
  }
  __syncthreads();
  const int o = t >> 1;
  const int mh = (t & 1) * 32;
  float* dst = out + B_ * M_ * 3 + (size_t)(b * 128 + o) * M_ + m0 + mh;
#pragma unroll
  for (int q = 0; q < 8; ++q) {
    float4 v;
    v.x = tile[o][mh + q * 4 + 0];
    v.y = tile[o][mh + q * 4 + 1];
    v.z = tile[o][mh + q * 4 + 2];
    v.w = tile[o][mh + q * 4 + 3];
    *(float4*)(dst + q * 4) = v;
  }
}

// ---------------------------------------------------------------------------
extern "C" void kernel_launch(void* const* d_in, const int* in_sizes, int n_in,
                              void* d_out, int out_size, void* d_ws, size_t ws_size,
                              hipStream_t stream) {
  (void)in_sizes; (void)n_in; (void)out_size;
  if (ws_size < WS_NEED) return;  // safety: fail cleanly, not with a memfault

  const float* xyz = (const float*)d_in[0];
  const float* feat = (const float*)d_in[1];
  const float* W1 = (const float*)d_in[2];
  const float* b1 = (const float*)d_in[3];
  const float* g1 = (const float*)d_in[4];
  const float* be1 = (const float*)d_in[5];
  const float* W2 = (const float*)d_in[6];
  const float* b2 = (const float*)d_in[7];
  const float* g2 = (const float*)d_in[8];
  const float* be2 = (const float*)d_in[9];
  const float* W3 = (const float*)d_in[10];
  const float* b3 = (const float*)d_in[11];
  const float* g3 = (const float*)d_in[12];
  const float* be3 = (const float*)d_in[13];
  float* out = (float*)d_out;
  char* ws = (char*)d_ws;

  int* knn = (int*)(ws + OFF_KNN);
  unsigned short* featB = (unsigned short*)(ws + OFF_FEATB);
  float* maxz = (float*)(ws + OFF_MAXZ);     // aliases featB (dead after k_l1)
  float* xyz4 = (float*)(ws + OFF_XYZ4);
  float* xn = (float*)(ws + OFF_XN);
  float* wt1 = (float*)(ws + OFF_WT1);
  float* wt2 = (float*)(ws + OFF_WT2);
  unsigned short* wt3f = (unsigned short*)(ws + OFF_WT3);
  unsigned short* w1f = (unsigned short*)(ws + OFF_W1F);
  unsigned short* w2f = (unsigned short*)(ws + OFF_W2F);
  float* gst = (float*)(ws + OFF_GST);
  unsigned short* z = (unsigned short*)(ws + OFF_Z);

  hipMemsetAsync(gst, 0, 512 * sizeof(float), stream);
  k_prep<<<385, 256, 0, stream>>>(xyz, feat, W1, W2, W3, featB, xyz4, xn,
                                  wt1, wt2, wt3f, w1f, w2f, out);
  k_knn<<<4096, 256, 0, stream>>>(xyz, xyz4, knn);
  k_l1<<<1024, 256, 0, stream>>>(xyz4, featB, knn, out, wt1, b1, w1f, z, gst);
  k_l2<<<1024, 256, 0, stream>>>(z, w2f, b2, gst, g1, be1, gst + 128);
  k_l3<<<1024, 256, 0, stream>>>(z, wt3f, b3, gst + 128, g2, be2, g3, maxz,
                                 gst + 256);
  k_final<<<256, 256, 0, stream>>>(maxz, gst + 256, g3, be3, out);
}

// Round 13
// 327.763 us; speedup vs baseline: 1.3671x; 1.1582x over previous
//
#include <hip/hip_runtime.h>
#include <cstdint>

// ---------------------------------------------------------------------------
// SA_Layer_PN2: centers + 32-NN + (gather,concat) -> 3x [1x1conv -> BN -> ReLU]
// -> max over k.  f32 math, bf16 activation storage.
// R25 (379.6us, PASS) = baseline: R22 MFMA layers + inlined BN-finalize +
// k_l1 gather prefetch. k_knn FROZEN (R19 form; R17/R24 showed the selection
// is codegen-fragile — do not restructure, do not touch d2key).
// R26: kill the ~3.4x z/featB read over-fetch (R23 steady k_l3 FETCH=225MB
// vs 85MB ideal). The quad-strided A-fragment loads (16B per lane at
// row*128 + quad*16) fetch ~4x per 16-lane group at >=64B granularity.
// Now each r-tile is staged into a wave-private LDS buffer with DENSE loads
// (lane i: 32B at row(i>>2)*128 + (i&3)*32 — 4 lanes cover a row
// contiguously), fragments then read from LDS (144B-padded rows, <=2-way
// bank alias = free). Bytes identical -> absmax must remain 0.0625.
// ---------------------------------------------------------------------------

constexpr int B_ = 8;
constexpr int N_ = 8192;
constexpr int M_ = 2048;
constexpr int K_ = 32;
constexpr float NTINV = 1.0f / 524288.0f;   // 1 / (B*M*K)
constexpr float BN_EPS = 1e-5f;

// workspace layout (bytes)
constexpr size_t OFF_KNN   = 0;             // int32 [B*M*K]          2,097,152
constexpr size_t OFF_FEATB = 2097152;       // bf16 [B*N*64]          8,388,608
constexpr size_t OFF_MAXZ  = 2097152;       // f32 [16384*128] ALIASES featB (dead after k_l1)
constexpr size_t OFF_XYZ4  = 10485760;      // f32x4 [B*N]            2,097,152
constexpr size_t OFF_XN    = 12582912;      // f32 [B*N]                262,144
constexpr size_t OFF_WT1   = 12845056;      // f32 [67*64]               17,152
constexpr size_t OFF_WT2   = 12862208;      // f32 [64*64]               16,384
constexpr size_t OFF_WT3   = 12878592;      // bf16 frags [8192]         16,384
constexpr size_t OFF_W1F   = 12894976;      // bf16 frags [4096]          8,192
constexpr size_t OFF_W2F   = 12903168;      // bf16 frags [4096]          8,192
constexpr size_t OFF_GST   = 12911360;      // f32 [512]
constexpr size_t OFF_SS1   = 12913408;      // f32 [128]  (unused now)
constexpr size_t OFF_SS2   = 12913920;      // f32 [128]  (unused now)
constexpr size_t OFF_Z     = 12914432;      // bf16 [524288*64]      67,108,864
constexpr size_t WS_NEED   = 80023296;      // ~80 MB total

typedef __attribute__((ext_vector_type(8))) short bf16x8;
typedef __attribute__((ext_vector_type(4))) float f32x4;

// ---- bf16 helpers (RNE) ----------------------------------------------------
__device__ __forceinline__ unsigned int pack_bf2(float a, float b) {
  unsigned int ua = __float_as_uint(a);
  unsigned int ub = __float_as_uint(b);
  ua = ua + 0x7FFFu + ((ua >> 16) & 1u);
  ub = ub + 0x7FFFu + ((ub >> 16) & 1u);
  return (ua >> 16) | (ub & 0xFFFF0000u);
}
__device__ __forceinline__ float bf_lo(unsigned int u) { return __uint_as_float(u << 16); }
__device__ __forceinline__ float bf_hi(unsigned int u) { return __uint_as_float(u & 0xFFFF0000u); }
// value as it will appear after bf16 store+reload (same arithmetic as pack_bf2)
__device__ __forceinline__ float bf_round(float x) {
  unsigned int u = __float_as_uint(x);
  u = (u + 0x7FFFu + ((u >> 16) & 1u)) & 0xFFFF0000u;
  return __uint_as_float(u);
}

// monotone key — VERIFIED expression (R2/R14/R18). Single inlined definition
// => identical lowering at every call site (pass1/pass2/fallback consistent).
__device__ __forceinline__ unsigned int d2key(const float4 pv, float cx, float cy,
                                              float cz, float cb) {
  const float dot = cx * pv.x + cy * pv.y + cz * pv.z;
  const float d2 = (cb + pv.w) - 2.0f * dot;          // same formula as ref
  const unsigned int bits = __float_as_uint(d2);
  return bits ^ ((unsigned int)((int)bits >> 31) | 0x80000000u);
}
__device__ __forceinline__ int cindex(int m) {
  return (int)(((long long)m * (N_ - 1)) / (M_ - 1));
}

// ---------------------------------------------------------------------------
// k_prep: featB (bf16) pack, xyz4 pad (norm in .w), weight transposes,
// centers, + W3/W1(cols 3..66)/W2 packed as MFMA B-fragments.
// ---------------------------------------------------------------------------
__global__ __launch_bounds__(256) void k_prep(
    const float* __restrict__ xyz, const float* __restrict__ feat,
    const float* __restrict__ W1, const float* __restrict__ W2,
    const float* __restrict__ W3,
    unsigned short* __restrict__ featB, float* __restrict__ xyz4,
    float* __restrict__ xn,
    float* __restrict__ wt1, float* __restrict__ wt2,
    unsigned short* __restrict__ wt3f,
    unsigned short* __restrict__ w1f, unsigned short* __restrict__ w2f,
    float* __restrict__ cent_out)
{
  const int id = blockIdx.x * 256 + threadIdx.x;
  if (id < B_ * N_) {
    const int b = id >> 13;
    const int n = id & (N_ - 1);
    const float* pp = xyz + id * 3;
    const float x = pp[0], y = pp[1], z = pp[2];
    const float nrm = x * x + y * y + z * z;
    xn[id] = nrm;
    float4* x4 = (float4*)xyz4;
    x4[id] = make_float4(x, y, z, nrm);
    const float* fsrc = feat + b * 64 * N_ + n;
    unsigned short* fdst = featB + (size_t)id * 64;
#pragma unroll
    for (int c8 = 0; c8 < 8; ++c8) {
      uint4 v;
      v.x = pack_bf2(fsrc[(c8 * 8 + 0) * N_], fsrc[(c8 * 8 + 1) * N_]);
      v.y = pack_bf2(fsrc[(c8 * 8 + 2) * N_], fsrc[(c8 * 8 + 3) * N_]);
      v.z = pack_bf2(fsrc[(c8 * 8 + 4) * N_], fsrc[(c8 * 8 + 5) * N_]);
      v.w = pack_bf2(fsrc[(c8 * 8 + 6) * N_], fsrc[(c8 * 8 + 7) * N_]);
      *(uint4*)(fdst + c8 * 8) = v;
    }
  } else if (id < B_ * N_ + B_ * M_) {
    const int idx = id - B_ * N_;
    const int b = idx >> 11;
    const int m = idx & (M_ - 1);
    const int ic = cindex(m);
    const float* cp = xyz + (b * N_ + ic) * 3;
    float* dst = cent_out + idx * 3;
    dst[0] = cp[0]; dst[1] = cp[1]; dst[2] = cp[2];
  } else if (id < 81920 + 4288) {
    const int i = id - 81920;
    const int c = i >> 6, o = i & 63;
    wt1[i] = W1[o * 67 + c];
  } else if (id < 86208 + 4096) {
    const int i = id - 86208;
    const int c = i >> 6, o = i & 63;
    wt2[c * 64 + o] = W2[o * 64 + c];
  } else if (id < 90304 + 1024) {
    const int f = id - 90304;           // f = (ct*2+ks)*64 + lane, ct 0..7
    const int ct = f >> 7;
    const int ks = (f >> 6) & 1;
    const int lane = f & 63;
    const int quad = lane >> 4;
    const int col = lane & 15;
    const int n = ct * 16 + col;
    const int kb = ks * 32 + quad * 8;
    const float* wr = W3 + n * 64 + kb;
    uint4 v;
    v.x = pack_bf2(wr[0], wr[1]);
    v.y = pack_bf2(wr[2], wr[3]);
    v.z = pack_bf2(wr[4], wr[5]);
    v.w = pack_bf2(wr[6], wr[7]);
    ((uint4*)wt3f)[f] = v;
  } else if (id < 91328 + 512) {
    const int f = id - 91328;           // W2 fragments: ct 0..3
    const int ct = f >> 7;
    const int ks = (f >> 6) & 1;
    const int lane = f & 63;
    const int quad = lane >> 4;
    const int col = lane & 15;
    const int n = ct * 16 + col;
    const int kb = ks * 32 + quad * 8;
    const float* wr = W2 + n * 64 + kb;
    uint4 v;
    v.x = pack_bf2(wr[0], wr[1]);
    v.y = pack_bf2(wr[2], wr[3]);
    v.z = pack_bf2(wr[4], wr[5]);
    v.w = pack_bf2(wr[6], wr[7]);
    ((uint4*)w2f)[f] = v;
  } else if (id < 91840 + 512) {
    const int f = id - 91840;           // W1 fragments (input cols 3..66)
    const int ct = f >> 7;
    const int ks = (f >> 6) & 1;
    const int lane = f & 63;
    const int quad = lane >> 4;
    const int col = lane & 15;
    const int n = ct * 16 + col;
    const int kb = ks * 32 + quad * 8;
    const float* wr = W1 + n * 67 + 3 + kb;
    uint4 v;
    v.x = pack_bf2(wr[0], wr[1]);
    v.y = pack_bf2(wr[2], wr[3]);
    v.z = pack_bf2(wr[4], wr[5]);
    v.w = pack_bf2(wr[6], wr[7]);
    ((uint4*)w1f)[f] = v;
  }
}

// ---------------------------------------------------------------------------
// k_knn R19: one block = 4 centers. Occupancy-tuned. FROZEN (structure,
// grid 4096, scalar-local key math — codegen-sensitive, do not restructure).
// ---------------------------------------------------------------------------
__global__ __launch_bounds__(256, 4) void k_knn(
    const float* __restrict__ xyz, const float* __restrict__ xyz4,
    int* __restrict__ knn)
{
  __shared__ unsigned int hist4[4][1024];       // 16 KB; reused as keys2[4][512]
  __shared__ int sh_cnt[4], sh_B4[4], wsum4[4][4];
  __shared__ unsigned long long wbest[4];

  unsigned long long* keys2 = (unsigned long long*)hist4;

  const int t = threadIdx.x;
  const int lane = t & 63;
  const int w = t >> 6;
  const int bid = blockIdx.x;
  const int b = bid >> 9;
  const int m0 = (bid & 511) * 4;
  const int row_base = (b * M_ + m0) * K_;
  const float4* pts = ((const float4*)xyz4) + b * N_;

  // centers (block-uniform scalar loads)
  const float* cp0 = xyz + (b * N_ + cindex(m0 + 0)) * 3;
  const float* cp1 = xyz + (b * N_ + cindex(m0 + 1)) * 3;
  const float* cp2 = xyz + (b * N_ + cindex(m0 + 2)) * 3;
  const float* cp3 = xyz + (b * N_ + cindex(m0 + 3)) * 3;
  const float cx0 = cp0[0], cy0 = cp0[1], cz0 = cp0[2];
  const float cx1 = cp1[0], cy1 = cp1[1], cz1 = cp1[2];
  const float cx2 = cp2[0], cy2 = cp2[1], cz2 = cp2[2];
  const float cx3 = cp3[0], cy3 = cp3[1], cz3 = cp3[2];
  const float cb0 = cx0 * cx0 + cy0 * cy0 + cz0 * cz0;
  const float cb1 = cx1 * cx1 + cy1 * cy1 + cz1 * cz1;
  const float cb2 = cx2 * cx2 + cy2 * cy2 + cz2 * cz2;
  const float cb3 = cx3 * cx3 + cy3 * cy3 + cz3 * cz3;

  // zero hist (16 KB) + counters
  {
    uint4* hz = (uint4*)hist4;
    const uint4 z4 = make_uint4(0u, 0u, 0u, 0u);
#pragma unroll
    for (int i = 0; i < 4; ++i) hz[t * 4 + i] = z4;
  }
  if (t < 4) sh_cnt[t] = 0;
  __syncthreads();

  // ---- pass 1: stream points once (batch-8 chunks), 4 running minima ----
  unsigned int um0 = 0xFFFFFFFFu, um1 = 0xFFFFFFFFu;
  unsigned int um2 = 0xFFFFFFFFu, um3 = 0xFFFFFFFFu;
#pragma unroll 1
  for (int jo = 0; jo < 4; ++jo) {
    float4 pv8[8];
#pragma unroll
    for (int ji = 0; ji < 8; ++ji) pv8[ji] = pts[t + 256 * (jo * 8 + ji)];
#pragma unroll
    for (int ji = 0; ji < 8; ++ji) {
      const float4 pv = pv8[ji];
      const unsigned int k0 = d2key(pv, cx0, cy0, cz0, cb0);
      const unsigned int k1 = d2key(pv, cx1, cy1, cz1, cb1);
      const unsigned int k2 = d2key(pv, cx2, cy2, cz2, cb2);
      const unsigned int k3 = d2key(pv, cx3, cy3, cz3, cb3);
      um0 = um0 < k0 ? um0 : k0;
      um1 = um1 < k1 ? um1 : k1;
      um2 = um2 < k2 ? um2 : k2;
      um3 = um3 < k3 ? um3 : k3;
    }
  }
  atomicAdd(&hist4[0][um0 >> 22], 1u);
  atomicAdd(&hist4[1][um1 >> 22], 1u);
  atomicAdd(&hist4[2][um2 >> 22], 1u);
  atomicAdd(&hist4[3][um3 >> 22], 1u);
  __syncthreads();

  // ---- fused 4 scans: thread t owns slots [4t, 4t+4) of each hist4[s] ----
  {
    unsigned int h4[4][4], incl[4], sum[4];
#pragma unroll
    for (int s = 0; s < 4; ++s) {
      const uint4 ha = ((const uint4*)&hist4[s][0])[t];
      h4[s][0] = ha.x; h4[s][1] = ha.y; h4[s][2] = ha.z; h4[s][3] = ha.w;
      sum[s] = ha.x + ha.y + ha.z + ha.w;
      incl[s] = sum[s];
    }
#pragma unroll
    for (int off = 1; off < 64; off <<= 1) {
#pragma unroll
      for (int s = 0; s < 4; ++s) {
        const unsigned int v = __shfl_up(incl[s], off);
        if (lane >= off) incl[s] += v;
      }
    }
    if (lane == 63) {
#pragma unroll
      for (int s = 0; s < 4; ++s) wsum4[s][w] = (int)incl[s];
    }
    __syncthreads();
#pragma unroll
    for (int s = 0; s < 4; ++s) {
      unsigned int wpre = 0;
#pragma unroll
      for (int i = 0; i < 4; ++i) wpre += (i < w) ? (unsigned int)wsum4[s][i] : 0u;
      const unsigned int excl = wpre + incl[s] - sum[s];   // minima in slots < 4t
      unsigned int run = excl;
      int Bq = -1;
#pragma unroll
      for (int q = 0; q < 4; ++q) { run += h4[s][q]; if (Bq < 0 && run >= 33) Bq = t * 4 + q; }
      if (Bq >= 0 && excl < 33) sh_B4[s] = Bq;             // unique crossing thread
    }
    __syncthreads();                                       // sh_B4 visible
  }

  const unsigned int Bb0 = (unsigned int)sh_B4[0];
  const unsigned int Bb1 = (unsigned int)sh_B4[1];
  const unsigned int Bb2 = (unsigned int)sh_B4[2];
  const unsigned int Bb3 = (unsigned int)sh_B4[3];

  // ---- pass 2: stream once more (batch-8), compact candidates ----
#pragma unroll 1
  for (int jo = 0; jo < 4; ++jo) {
    float4 pv8[8];
#pragma unroll
    for (int ji = 0; ji < 8; ++ji) pv8[ji] = pts[t + 256 * (jo * 8 + ji)];
#pragma unroll
    for (int ji = 0; ji < 8; ++ji) {
      const float4 pv = pv8[ji];
      const unsigned int idx = (unsigned int)(t + 256 * (jo * 8 + ji));
      const unsigned int k0 = d2key(pv, cx0, cy0, cz0, cb0);
      const unsigned int k1 = d2key(pv, cx1, cy1, cz1, cb1);
      const unsigned int k2 = d2key(pv, cx2, cy2, cz2, cb2);
      const unsigned int k3 = d2key(pv, cx3, cy3, cz3, cb3);
      if ((k0 >> 22) <= Bb0) {
        const int pos = atomicAdd(&sh_cnt[0], 1);
        if (pos < 512) keys2[0 * 512 + pos] = ((unsigned long long)k0 << 32) | idx;
      }
      if ((k1 >> 22) <= Bb1) {
        const int pos = atomicAdd(&sh_cnt[1], 1);
        if (pos < 512) keys2[1 * 512 + pos] = ((unsigned long long)k1 << 32) | idx;
      }
      if ((k2 >> 22) <= Bb2) {
        const int pos = atomicAdd(&sh_cnt[2], 1);
        if (pos < 512) keys2[2 * 512 + pos] = ((unsigned long long)k2 << 32) | idx;
      }
      if ((k3 >> 22) <= Bb3) {
        const int pos = atomicAdd(&sh_cnt[3], 1);
        if (pos < 512) keys2[3 * 512 + pos] = ((unsigned long long)k3 << 32) | idx;
      }
    }
  }
  __syncthreads();

  // ---- rank: wave w ranks center w (exact 64-bit rank, broadcast reads) ----
  {
    const int C = sh_cnt[w];
    if (C <= 512) {
      const unsigned long long* kk = keys2 + w * 512;
      int* row = knn + row_base + w * K_;
      for (int i = lane; i < C; i += 64) {
        const unsigned long long k = kk[i];
        int r = 0;
        for (int q = 0; q < C; ++q) r += (kk[q] < k) ? 1 : 0;
        if (r < K_) row[r] = (int)(k & 0xFFFFFFFFull);
      }
    }
  }
  __syncthreads();

  // ---- fallback (practically never): exact 32-round extraction ----
#pragma unroll
  for (int s = 0; s < 4; ++s) {
    if (sh_cnt[s] > 512) {                         // block-uniform
      const float cx = (s == 0) ? cx0 : (s == 1) ? cx1 : (s == 2) ? cx2 : cx3;
      const float cy = (s == 0) ? cy0 : (s == 1) ? cy1 : (s == 2) ? cy2 : cy3;
      const float cz = (s == 0) ? cz0 : (s == 1) ? cz1 : (s == 2) ? cz2 : cz3;
      const float cb = (s == 0) ? cb0 : (s == 1) ? cb1 : (s == 2) ? cb2 : cb3;
      unsigned int uu[32];
#pragma unroll
      for (int j = 0; j < 32; ++j) uu[j] = d2key(pts[t + 256 * j], cx, cy, cz, cb);
      int* row = knn + row_base + s * K_;
#pragma unroll 1
      for (int r = 0; r < K_; ++r) {
        unsigned long long best = 0xFFFFFFFFFFFFFFFFull;
#pragma unroll
        for (int j = 0; j < 32; ++j) {
          unsigned long long k = ((unsigned long long)uu[j] << 32) | (unsigned int)(t + 256 * j);
          best = (k < best) ? k : best;
        }
#pragma unroll
        for (int off = 1; off < 64; off <<= 1) {
          unsigned long long o = __shfl_xor(best, off);
          best = (o < best) ? o : best;
        }
        if (lane == 0) wbest[w] = best;
        __syncthreads();
        unsigned long long b01 = wbest[0] < wbest[1] ? wbest[0] : wbest[1];
        unsigned long long b23 = wbest[2] < wbest[3] ? wbest[2] : wbest[3];
        best = b01 < b23 ? b01 : b23;
        if (t == 0) row[r] = (int)(best & 0xFFFFFFFFull);
        const int n_match = (int)(best & 0xFFFFFFFFull);
#pragma unroll
        for (int j = 0; j < 32; ++j)
          if ((t + 256 * j) == n_match) uu[j] = 0xFFFFFFFFu;
        __syncthreads();
      }
    }
  }
}

// ---------------------------------------------------------------------------
// k_l1 v5c (MFMA, dense-staged gather): wave owns 4 centers (2 r-tiles).
// Each r-tile's 16 gathered featB rows are staged into a wave-private LDS
// tile with DENSE loads (4 lanes x 32B per row), then A-fragments read from
// LDS (144B-padded rows). B-frag = w1f. Epilogue unchanged (f32 local-xyz
// + b1, bf16-round, fused stats, tp transpose, coalesced z store).
// ---------------------------------------------------------------------------
__global__ __launch_bounds__(256, 4) void k_l1(
    const float* __restrict__ xyz4, const unsigned short* __restrict__ featB,
    const int* __restrict__ knn, const float* __restrict__ centers,
    const float* __restrict__ wt1, const float* __restrict__ bias,
    const unsigned short* __restrict__ w1f,
    unsigned short* __restrict__ zout, float* __restrict__ gstats)
{
  __shared__ unsigned short wfl[4096];        // 8 KB W1 fragments
  __shared__ float tp[4][16][68];             // per-wave transpose tiles
  __shared__ unsigned short zt[4][16 * 72];   // per-wave staged rows (144B pitch)
  __shared__ float ls[128];
  const int t = threadIdx.x;
  const int lane = t & 63;
  const int w = t >> 6;
  const int quad = lane >> 4;
  const int col = lane & 15;

  {
    const uint4* src = (const uint4*)w1f;
    uint4* dst = (uint4*)wfl;
    dst[t] = src[t];
    dst[t + 256] = src[t + 256];
  }
  if (t < 128) ls[t] = 0.0f;
  __syncthreads();

  // per-lane channel consts: ch = ct*16+col
  float w1x[4], w1y[4], w1z[4], b14[4];
#pragma unroll
  for (int ct = 0; ct < 4; ++ct) {
    const int ch = ct * 16 + col;
    w1x[ct] = wt1[ch];
    w1y[ct] = wt1[64 + ch];
    w1z[ct] = wt1[128 + ch];
    b14[ct] = bias[ch];
  }

  float sacc[4] = {0.f, 0.f, 0.f, 0.f};
  float qacc[4] = {0.f, 0.f, 0.f, 0.f};

  const int c0 = blockIdx.x * 16 + w * 4;     // 1024 blocks, 16 centers each
  const int srow = lane >> 2, soff = lane & 3;   // dense staging mapping

#pragma unroll 1
  for (int ci = 0; ci < 4; ++ci) {
    const int c = c0 + ci;                    // global center id
    const int b = c >> 11;
    const float* cp = centers + c * 3;        // wave-uniform
    const float cx = cp[0], cy = cp[1], cz = cp[2];

    // prefetch both r-tiles' gather state (load reorder only; values same)
    const int nnA = knn[c * 32 + col];
    const int nnB = knn[c * 32 + 16 + col];
    const float4 pvA = ((const float4*)xyz4)[b * N_ + nnA];
    const float4 pvB = ((const float4*)xyz4)[b * N_ + nnB];

#pragma unroll 1
    for (int rt = 0; rt < 2; ++rt) {
      const int pbase = c * 32 + rt * 16;
      const int nn = rt ? nnB : nnA;
      const float4 pv = rt ? pvB : pvA;
      const float l0 = pv.x - cx;
      const float l1 = pv.y - cy;
      const float l2 = pv.z - cz;

      // dense staging: lane covers 32B of row srow (4 lanes/row contiguous)
      {
        const int nnS = __shfl(nn, srow);
        const uint4* srcp = (const uint4*)(featB + ((size_t)b * N_ + nnS) * 64 + soff * 16);
        uint4* td = (uint4*)&zt[w][srow * 72 + soff * 16];
        td[0] = srcp[0];
        td[1] = srcp[1];
      }
      asm volatile("s_waitcnt lgkmcnt(0)" ::: "memory");

      bf16x8 afr[2];
#pragma unroll
      for (int ks = 0; ks < 2; ++ks) {
        union { uint4 u; bf16x8 v; } cv;
        cv.u = *(const uint4*)&zt[w][col * 72 + ks * 32 + quad * 8];
        afr[ks] = cv.v;
      }

      f32x4 acc[4];
#pragma unroll
      for (int ct = 0; ct < 4; ++ct) acc[ct] = (f32x4){0.f, 0.f, 0.f, 0.f};
#pragma unroll
      for (int ct = 0; ct < 4; ++ct) {
        const bf16x8 b0 = *(const bf16x8*)(wfl + ((ct * 2 + 0) * 64 + lane) * 8);
        const bf16x8 b1 = *(const bf16x8*)(wfl + ((ct * 2 + 1) * 64 + lane) * 8);
        acc[ct] = __builtin_amdgcn_mfma_f32_16x16x32_bf16(afr[0], b0, acc[ct], 0, 0, 0);
        acc[ct] = __builtin_amdgcn_mfma_f32_16x16x32_bf16(afr[1], b1, acc[ct], 0, 0, 0);
      }

      // epilogue: + local_xyz part (f32) + bias, round, stats, LDS tile
#pragma unroll
      for (int i = 0; i < 4; ++i) {
        const int srcl = quad * 4 + i;        // D point row = quad*4+i
        const float lx = __shfl(l0, srcl);
        const float ly = __shfl(l1, srcl);
        const float lz = __shfl(l2, srcl);
#pragma unroll
        for (int ct = 0; ct < 4; ++ct) {
          const float v = fmaf(lx, w1x[ct],
                          fmaf(ly, w1y[ct],
                          fmaf(lz, w1z[ct], b14[ct]))) + acc[ct][i];
          const float rv = bf_round(v);
          sacc[ct] += rv;
          qacc[ct] = fmaf(rv, rv, qacc[ct]);
          tp[w][quad * 4 + i][ct * 16 + col] = rv;
        }
      }
      asm volatile("s_waitcnt lgkmcnt(0)" ::: "memory");

      // transpose store: lane -> point (lane>>2), channel chunk (lane&3)*16
      {
        const int pi = lane >> 2, cc = lane & 3;
        const float* tr = &tp[w][pi][cc * 16];
        unsigned int o[8];
#pragma unroll
        for (int j = 0; j < 8; ++j) o[j] = pack_bf2(tr[2 * j], tr[2 * j + 1]);
        unsigned short* zp = zout + (size_t)(pbase + pi) * 64 + cc * 16;
        *(uint4*)zp = make_uint4(o[0], o[1], o[2], o[3]);
        *(uint4*)(zp + 8) = make_uint4(o[4], o[5], o[6], o[7]);
      }
      asm volatile("s_waitcnt lgkmcnt(0)" ::: "memory");
    }
  }

  // fused layer-1 stats: channel ct*16+col replicated across quads
#pragma unroll
  for (int ct = 0; ct < 4; ++ct) {
    float sv = sacc[ct], qv = qacc[ct];
    sv += __shfl_xor(sv, 16);
    sv += __shfl_xor(sv, 32);
    qv += __shfl_xor(qv, 16);
    qv += __shfl_xor(qv, 32);
    if (quad == 0) {
      atomicAdd(&ls[ct * 16 + col], sv);
      atomicAdd(&ls[64 + ct * 16 + col], qv);
    }
  }
  __syncthreads();
  if (t < 128) atomicAdd(&gstats[t], ls[t]);  // s[0..63], q[64..127]
}

// ---------------------------------------------------------------------------
// k_l2 v2c (MFMA, in-place, dense-staged z reads, inlined BN1-finalize):
// block prologue computes ss1 from gstats (bit-exact k_bnfin formula).
// Each r-tile's 16 z rows staged densely into wave-private LDS; A-build
// (BN1+ReLU) reads from LDS. Epilogue unchanged.
// ---------------------------------------------------------------------------
__global__ __launch_bounds__(256, 4) void k_l2(
    unsigned short* __restrict__ z, const unsigned short* __restrict__ w2f,
    const float* __restrict__ bias,
    const float* __restrict__ gst_in, const float* __restrict__ g,
    const float* __restrict__ be,
    float* __restrict__ gstats)
{
  __shared__ unsigned short wfl[4096];        // 8 KB W2 fragments
  __shared__ float tp[4][16][68];
  __shared__ unsigned short zt[4][16 * 72];   // per-wave staged rows
  __shared__ float ls[128];
  __shared__ float ssl[128];
  const int t = threadIdx.x;
  const int lane = t & 63;
  const int w = t >> 6;
  const int quad = lane >> 4;
  const int col = lane & 15;

  {
    const uint4* src = (const uint4*)w2f;
    uint4* dst = (uint4*)wfl;
    dst[t] = src[t];
    dst[t + 256] = src[t + 256];
  }
  if (t < 64) {                               // inlined k_bnfin (bit-exact)
    const float s = gst_in[t], q = gst_in[64 + t];
    const float mu = s * NTINV;
    const float var = q * NTINV - mu * mu;
    const float scale = g[t] * rsqrtf(var + BN_EPS);
    ssl[t] = scale;
    ssl[64 + t] = be[t] - mu * scale;
  }
  if (t < 128) ls[t] = 0.0f;
  __syncthreads();

  const float4* scv = (const float4*)ssl;
  const float4* shv = (const float4*)(ssl + 64);

  float b24[4];
#pragma unroll
  for (int ct = 0; ct < 4; ++ct) b24[ct] = bias[ct * 16 + col];

  float sacc[4] = {0.f, 0.f, 0.f, 0.f};
  float qacc[4] = {0.f, 0.f, 0.f, 0.f};

  const int c0 = blockIdx.x * 16 + w * 4;
  const int srow = lane >> 2, soff = lane & 3;

#pragma unroll 1
  for (int ci = 0; ci < 4; ++ci) {
    const int c = c0 + ci;
#pragma unroll 1
    for (int rt = 0; rt < 2; ++rt) {
      const int pbase = c * 32 + rt * 16;

      // dense staging of 16 contiguous z rows
      {
        const uint4* srcp = (const uint4*)(z + (size_t)(pbase + srow) * 64 + soff * 16);
        uint4* td = (uint4*)&zt[w][srow * 72 + soff * 16];
        td[0] = srcp[0];
        td[1] = srcp[1];
      }
      asm volatile("s_waitcnt lgkmcnt(0)" ::: "memory");

      // A-build: read 16B from LDS, BN1+ReLU, repack bf16 (values identical)
      bf16x8 afr[2];
#pragma unroll
      for (int ks = 0; ks < 2; ++ks) {
        const int k0 = ks * 32 + quad * 8;
        union { uint4 u; bf16x8 v; } rawu;
        rawu.u = *(const uint4*)&zt[w][col * 72 + k0];
        const uint4 raw = rawu.u;
        const float4 s0 = scv[k0 >> 2], s1 = scv[(k0 >> 2) + 1];
        const float4 h0 = shv[k0 >> 2], h1 = shv[(k0 >> 2) + 1];
        const float f0 = fmaxf(0.0f, fmaf(bf_lo(raw.x), s0.x, h0.x));
        const float f1 = fmaxf(0.0f, fmaf(bf_hi(raw.x), s0.y, h0.y));
        const float f2 = fmaxf(0.0f, fmaf(bf_lo(raw.y), s0.z, h0.z));
        const float f3 = fmaxf(0.0f, fmaf(bf_hi(raw.y), s0.w, h0.w));
        const float f4 = fmaxf(0.0f, fmaf(bf_lo(raw.z), s1.x, h1.x));
        const float f5 = fmaxf(0.0f, fmaf(bf_hi(raw.z), s1.y, h1.y));
        const float f6 = fmaxf(0.0f, fmaf(bf_lo(raw.w), s1.z, h1.z));
        const float f7 = fmaxf(0.0f, fmaf(bf_hi(raw.w), s1.w, h1.w));
        union { uint4 u; bf16x8 v; } cv;
        cv.u.x = pack_bf2(f0, f1);
        cv.u.y = pack_bf2(f2, f3);
        cv.u.z = pack_bf2(f4, f5);
        cv.u.w = pack_bf2(f6, f7);
        afr[ks] = cv.v;
      }

      f32x4 acc[4];
#pragma unroll
      for (int ct = 0; ct < 4; ++ct) acc[ct] = (f32x4){0.f, 0.f, 0.f, 0.f};
#pragma unroll
      for (int ct = 0; ct < 4; ++ct) {
        const bf16x8 b0 = *(const bf16x8*)(wfl + ((ct * 2 + 0) * 64 + lane) * 8);
        const bf16x8 b1 = *(const bf16x8*)(wfl + ((ct * 2 + 1) * 64 + lane) * 8);
        acc[ct] = __builtin_amdgcn_mfma_f32_16x16x32_bf16(afr[0], b0, acc[ct], 0, 0, 0);
        acc[ct] = __builtin_amdgcn_mfma_f32_16x16x32_bf16(afr[1], b1, acc[ct], 0, 0, 0);
      }

#pragma unroll
      for (int i = 0; i < 4; ++i) {
#pragma unroll
        for (int ct = 0; ct < 4; ++ct) {
          const float v = acc[ct][i] + b24[ct];
          const float rv = bf_round(v);
          sacc[ct] += rv;
          qacc[ct] = fmaf(rv, rv, qacc[ct]);
          tp[w][quad * 4 + i][ct * 16 + col] = rv;
        }
      }
      asm volatile("s_waitcnt lgkmcnt(0)" ::: "memory");

      {
        const int pi = lane >> 2, cc = lane & 3;
        const float* tr = &tp[w][pi][cc * 16];
        unsigned int o[8];
#pragma unroll
        for (int j = 0; j < 8; ++j) o[j] = pack_bf2(tr[2 * j], tr[2 * j + 1]);
        unsigned short* zp = z + (size_t)(pbase + pi) * 64 + cc * 16;
        *(uint4*)zp = make_uint4(o[0], o[1], o[2], o[3]);
        *(uint4*)(zp + 8) = make_uint4(o[4], o[5], o[6], o[7]);
      }
      asm volatile("s_waitcnt lgkmcnt(0)" ::: "memory");
    }
  }

#pragma unroll
  for (int ct = 0; ct < 4; ++ct) {
    float sv = sacc[ct], qv = qacc[ct];
    sv += __shfl_xor(sv, 16);
    sv += __shfl_xor(sv, 32);
    qv += __shfl_xor(qv, 16);
    qv += __shfl_xor(qv, 32);
    if (quad == 0) {
      atomicAdd(&ls[ct * 16 + col], sv);
      atomicAdd(&ls[64 + ct * 16 + col], qv);
    }
  }
  __syncthreads();
  if (t < 128) atomicAdd(&gstats[t], ls[t]);  // s[0..63], q[64..127]
}

// ---------------------------------------------------------------------------
// k_l3 v8c (MFMA, register epilogue, dense-staged z reads, inlined BN2-
// finalize): block prologue computes ss2 from gstats (bit-exact k_bnfin).
// ---------------------------------------------------------------------------
__global__ __launch_bounds__(256, 4) void k_l3(
    const unsigned short* __restrict__ zin,
    const unsigned short* __restrict__ wf,
    const float* __restrict__ bias,
    const float* __restrict__ gst_in, const float* __restrict__ g2v,
    const float* __restrict__ be2v,
    const float* __restrict__ gvec, float* __restrict__ maxz,
    float* __restrict__ gstats)
{
  __shared__ float ls[256];
  __shared__ unsigned short wfl[8192];        // 16 KB fragment table (LDS copy)
  __shared__ unsigned short zt[4][16 * 72];   // per-wave staged rows
  __shared__ float ssl[128];                  // BN2 scale/shift (computed)
  const int t = threadIdx.x;
  const int lane = t & 63;
  const int w = t >> 6;
  const int quad = lane >> 4;
  const int col = lane & 15;

  // stage wf (1024 x uint4 = 16 KB) + compute ss2, zero ls
  {
    const uint4* wsrc = (const uint4*)wf;
    uint4* wdst = (uint4*)wfl;
#pragma unroll
    for (int i = 0; i < 4; ++i) wdst[t + 256 * i] = wsrc[t + 256 * i];
  }
  if (t < 64) {                               // inlined k_bnfin (bit-exact)
    const float s = gst_in[t], q = gst_in[64 + t];
    const float mu = s * NTINV;
    const float var = q * NTINV - mu * mu;
    const float scale = g2v[t] * rsqrtf(var + BN_EPS);
    ssl[t] = scale;
    ssl[64 + t] = be2v[t] - mu * scale;
  }
  ls[t] = 0.0f;
  __syncthreads();

  const int c0 = blockIdx.x * 16 + w * 4;     // 1024 blocks, 16 centers each
  const int srow = lane >> 2, soff = lane & 3;

  const float4* scv = (const float4*)ssl;
  const float4* shv = (const float4*)(ssl + 64);

  // per-lane channel constants: ch(ct) = ct*16+col
  float bo[8];
  bool up[8];
#pragma unroll
  for (int ct = 0; ct < 8; ++ct) {
    bo[ct] = bias[ct * 16 + col];
    up[ct] = (gvec[ct * 16 + col] >= 0.0f);
  }

  float sacc[8], qacc[8];
#pragma unroll
  for (int ct = 0; ct < 8; ++ct) { sacc[ct] = 0.0f; qacc[ct] = 0.0f; }

#pragma unroll 1
  for (int ci = 0; ci < 4; ++ci) {
    const int c = c0 + ci;
    float mx[8];

#pragma unroll 1
    for (int r = 0; r < 2; ++r) {
      const int pbase = c * 32 + r * 16;

      // dense staging of 16 contiguous z rows
      {
        const uint4* srcp = (const uint4*)(zin + (size_t)(pbase + srow) * 64 + soff * 16);
        uint4* td = (uint4*)&zt[w][srow * 72 + soff * 16];
        td[0] = srcp[0];
        td[1] = srcp[1];
      }
      asm volatile("s_waitcnt lgkmcnt(0)" ::: "memory");

      // build A-fragments (ks=0,1): read 16B from LDS, BN2+ReLU, repack bf16
      bf16x8 afr[2];
#pragma unroll
      for (int ks = 0; ks < 2; ++ks) {
        const int k0 = ks * 32 + quad * 8;
        union { uint4 u; bf16x8 v; } rawu;
        rawu.u = *(const uint4*)&zt[w][col * 72 + k0];
        const uint4 raw = rawu.u;
        const float4 s0 = scv[k0 >> 2], s1 = scv[(k0 >> 2) + 1];
        const float4 h0 = shv[k0 >> 2], h1 = shv[(k0 >> 2) + 1];
        const float f0 = fmaxf(0.0f, fmaf(bf_lo(raw.x), s0.x, h0.x));
        const float f1 = fmaxf(0.0f, fmaf(bf_hi(raw.x), s0.y, h0.y));
        const float f2 = fmaxf(0.0f, fmaf(bf_lo(raw.y), s0.z, h0.z));
        const float f3 = fmaxf(0.0f, fmaf(bf_hi(raw.y), s0.w, h0.w));
        const float f4 = fmaxf(0.0f, fmaf(bf_lo(raw.z), s1.x, h1.x));
        const float f5 = fmaxf(0.0f, fmaf(bf_hi(raw.z), s1.y, h1.y));
        const float f6 = fmaxf(0.0f, fmaf(bf_lo(raw.w), s1.z, h1.z));
        const float f7 = fmaxf(0.0f, fmaf(bf_hi(raw.w), s1.w, h1.w));
        union { uint4 u; bf16x8 v; } cv;
        cv.u.x = pack_bf2(f0, f1);
        cv.u.y = pack_bf2(f2, f3);
        cv.u.z = pack_bf2(f4, f5);
        cv.u.w = pack_bf2(f6, f7);
        afr[ks] = cv.v;
      }

      f32x4 acc[8];
#pragma unroll
      for (int ct = 0; ct < 8; ++ct) acc[ct] = (f32x4){0.f, 0.f, 0.f, 0.f};

#pragma unroll
      for (int ct = 0; ct < 8; ++ct) {
        const bf16x8 b0 = *(const bf16x8*)(wfl + ((ct * 2 + 0) * 64 + lane) * 8);
        const bf16x8 b1 = *(const bf16x8*)(wfl + ((ct * 2 + 1) * 64 + lane) * 8);
        acc[ct] = __builtin_amdgcn_mfma_f32_16x16x32_bf16(afr[0], b0, acc[ct], 0, 0, 0);
        acc[ct] = __builtin_amdgcn_mfma_f32_16x16x32_bf16(afr[1], b1, acc[ct], 0, 0, 0);
      }

      // in-register epilogue: bias, stats, tile-local max
#pragma unroll
      for (int ct = 0; ct < 8; ++ct) {
        const float v0 = acc[ct][0] + bo[ct];
        const float v1 = acc[ct][1] + bo[ct];
        const float v2 = acc[ct][2] + bo[ct];
        const float v3 = acc[ct][3] + bo[ct];
        sacc[ct] += (v0 + v1) + (v2 + v3);
        float qq = fmaf(v0, v0, qacc[ct]);
        qq = fmaf(v1, v1, qq);
        qq = fmaf(v2, v2, qq);
        qacc[ct] = fmaf(v3, v3, qq);
        const float m4 = up[ct]
            ? fmaxf(fmaxf(v0, v1), fmaxf(v2, v3))
            : fminf(fminf(v0, v1), fminf(v2, v3));
        mx[ct] = (r == 0) ? m4
                          : (up[ct] ? fmaxf(mx[ct], m4) : fminf(mx[ct], m4));
      }
    }

    // cross-quad combine (16 pts/quad-slice -> 32 pts) and store
#pragma unroll
    for (int ct = 0; ct < 8; ++ct) {
      float m = mx[ct];
      const float o1 = __shfl_xor(m, 16);
      m = up[ct] ? fmaxf(m, o1) : fminf(m, o1);
      const float o2 = __shfl_xor(m, 32);
      m = up[ct] ? fmaxf(m, o2) : fminf(m, o2);
      if (quad == 0) maxz[(size_t)c * 128 + ct * 16 + col] = m;
    }
  }

  // stats: cross-quad reduce, aggregate in LDS, one global atomic per thread
#pragma unroll
  for (int ct = 0; ct < 8; ++ct) {
    float sv = sacc[ct], qv = qacc[ct];
    sv += __shfl_xor(sv, 16);
    sv += __shfl_xor(sv, 32);
    qv += __shfl_xor(qv, 16);
    qv += __shfl_xor(qv, 32);
    if (quad == 0) {
      atomicAdd(&ls[ct * 16 + col], sv);
      atomicAdd(&ls[128 + ct * 16 + col], qv);
    }
  }
  __syncthreads();
  atomicAdd(&gstats[t], ls[t]);              // 256 slots: s[0..127], q[128..255]
}

// ---------------------------------------------------------------------------
// k_final: finalize BN3, apply to pooled extremes, ReLU, transpose to (B,128,M)
// gstats layout here: s at [ch], q at [128+ch].
// ---------------------------------------------------------------------------
__global__ __launch_bounds__(256) void k_final(
    const float* __restrict__ maxz, const float* __restrict__ gstats,
    const float* __restrict__ g, const float* __restrict__ be,
    float* __restrict__ out)
{
  __shared__ float sc[128], sh[128];
  __shared__ float tile[128][65];
  const int t = threadIdx.x;
  const int b = blockIdx.x >> 5;
  const int m0 = (blockIdx.x & 31) * 64;
  if (t < 128) {
    const float s = gstats[t], q = gstats[128 + t];
    const float mu = s * NTINV;
    const float var = q * NTINV - mu * mu;
    const float scale = g[t] * rsqrtf(var + BN_EPS);
    sc[t] = scale;
    sh[t] = be[t] - mu * scale;
  }
  __syncthreads();
  const float* src = maxz + (size_t)(b * M_ + m0) * 128;
#pragma unroll
  for (int r = 0; r < 8; ++r) {
    const int flat = r * 1024 + t * 4;
    const int ml = flat >> 7;
    const int o = flat & 127;
    const float4 v = *(const float4*)(src + flat);
    tile[o + 0][ml] = fmaxf(0.0f, fmaf(v.x, sc[o + 0], sh[o + 0]));
    tile[o + 1][ml] = fmaxf(0.0f, fmaf(v.y, sc[o + 1], sh[o + 1]));
    tile[o + 2][ml] = fmaxf(0.0f, fmaf(v.z, sc[o + 2], sh[o + 2]));
    tile[o + 3][ml] = fmaxf(0.0f, fmaf(v.w, sc[o + 3], sh[o + 3]));
  }
  __syncthreads();
  const int o = t >> 1;
  const int mh = (t & 1) * 32;
  float* dst = out + B_ * M_ * 3 + (size_t)(b * 128 + o) * M_ + m0 + mh;
#pragma unroll
  for (int q = 0; q < 8; ++q) {
    float4 v;
    v.x = tile[o][mh + q * 4 + 0];
    v.y = tile[o][mh + q * 4 + 1];
    v.z = tile[o][mh + q * 4 + 2];
    v.w = tile[o][mh + q * 4 + 3];
    *(float4*)(dst + q * 4) = v;
  }
}

// ---------------------------------------------------------------------------
extern "C" void kernel_launch(void* const* d_in, const int* in_sizes, int n_in,
                              void* d_out, int out_size, void* d_ws, size_t ws_size,
                              hipStream_t stream) {
  (void)in_sizes; (void)n_in; (void)out_size;
  if (ws_size < WS_NEED) return;  // safety: fail cleanly, not with a memfault

  const float* xyz = (const float*)d_in[0];
  const float* feat = (const float*)d_in[1];
  const float* W1 = (const float*)d_in[2];
  const float* b1 = (const float*)d_in[3];
  const float* g1 = (const float*)d_in[4];
  const float* be1 = (const float*)d_in[5];
  const float* W2 = (const float*)d_in[6];
  const float* b2 = (const float*)d_in[7];
  const float* g2 = (const float*)d_in[8];
  const float* be2 = (const float*)d_in[9];
  const float* W3 = (const float*)d_in[10];
  const float* b3 = (const float*)d_in[11];
  const float* g3 = (const float*)d_in[12];
  const float* be3 = (const float*)d_in[13];
  float* out = (float*)d_out;
  char* ws = (char*)d_ws;

  int* knn = (int*)(ws + OFF_KNN);
  unsigned short* featB = (unsigned short*)(ws + OFF_FEATB);
  float* maxz = (float*)(ws + OFF_MAXZ);     // aliases featB (dead after k_l1)
  float* xyz4 = (float*)(ws + OFF_XYZ4);
  float* xn = (float*)(ws + OFF_XN);
  float* wt1 = (float*)(ws + OFF_WT1);
  float* wt2 = (float*)(ws + OFF_WT2);
  unsigned short* wt3f = (unsigned short*)(ws + OFF_WT3);
  unsigned short* w1f = (unsigned short*)(ws + OFF_W1F);
  unsigned short* w2f = (unsigned short*)(ws + OFF_W2F);
  float* gst = (float*)(ws + OFF_GST);
  unsigned short* z = (unsigned short*)(ws + OFF_Z);

  hipMemsetAsync(gst, 0, 512 * sizeof(float), stream);
  k_prep<<<385, 256, 0, stream>>>(xyz, feat, W1, W2, W3, featB, xyz4, xn,
                                  wt1, wt2, wt3f, w1f, w2f, out);
  k_knn<<<4096, 256, 0, stream>>>(xyz, xyz4, knn);
  k_l1<<<1024, 256, 0, stream>>>(xyz4, featB, knn, out, wt1, b1, w1f, z, gst);
  k_l2<<<1024, 256, 0, stream>>>(z, w2f, b2, gst, g1, be1, gst + 128);
  k_l3<<<1024, 256, 0, stream>>>(z, wt3f, b3, gst + 128, g2, be2, g3, maxz,
                                 gst + 256);
  k_final<<<256, 256, 0, stream>>>(maxz, gst + 256, g3, be3, out);
}